// Round 4
// baseline (288.049 us; speedup 1.0000x reference)
//
#include <hip/hip_runtime.h>
#include <hip/hip_fp16.h>

typedef unsigned short u16;
typedef unsigned int u32;
typedef __attribute__((ext_vector_type(4))) float f32x4;
typedef __attribute__((ext_vector_type(8))) short s16x8;
typedef __attribute__((ext_vector_type(2))) unsigned int u32x2;
typedef __fp16 fp16x2 __attribute__((ext_vector_type(2)));

#define B_SZ 2
#define N_SZ 2048
#define H_SZ 8
#define DK 64
#define DM 512
// 0.125 * log2(e): folds 1/sqrt(dk) AND base-e->base-2 into Q projection weights
#define QSC 0.18033688f

static __device__ inline void mfma_f16(f32x4& acc, s16x8 a, s16x8 b) {
    asm volatile("v_mfma_f32_16x16x32_f16 %0, %1, %2, %0" : "+v"(acc) : "v"(a), "v"(b));
}
static __device__ inline u16 f16_rn(float f) { return __half_as_ushort(__float2half(f)); }

static __device__ inline u32 pkrtz(float a, float b) {
    union { fp16x2 h; u32 u; } cv;
    cv.h = __builtin_amdgcn_cvt_pkrtz(a, b);
    return cv.u;
}

#define EXP2(x) exp2f(x)

static __device__ inline s16x8 cvt8(const float4& a, const float4& b) {
    s16x8 r;
    r[0] = (short)f16_rn(a.x); r[1] = (short)f16_rn(a.y);
    r[2] = (short)f16_rn(a.z); r[3] = (short)f16_rn(a.w);
    r[4] = (short)f16_rn(b.x); r[5] = (short)f16_rn(b.y);
    r[6] = (short)f16_rn(b.z); r[7] = (short)f16_rn(b.w);
    return r;
}

// XOR swizzle for 128B LDS rows (GEMM A-tiles only)
static __device__ inline const u16* swzc(const u16* base, int row, int byteoff) {
    return (const u16*)((const char*)base + row * 128 + (byteoff ^ ((row & 7) << 4)));
}

#if __has_builtin(__builtin_amdgcn_global_load_lds)
#define HAS_GLL 1
static __device__ inline void gll16(const u16* g, u16* l) {
    __builtin_amdgcn_global_load_lds(
        (const __attribute__((address_space(1))) unsigned int*)g,
        (__attribute__((address_space(3))) unsigned int*)l, 16, 0, 0);
}
#endif
static __device__ inline void stage16(const u16* gp, u16* lbase, int lane) {
#ifdef HAS_GLL
    gll16(gp, lbase);
#else
    *(s16x8*)(lbase + lane * 8) = *(const s16x8*)(gp);
#endif
}

// ---------------------------------------------------------------------------
// K0: all prep.
//  blk 0..191    : proj transpose -> Pt [(z*8+h)*64+dk][512] fp16 (z=0 scaled QSC)
//  blk 192..319  : w_out fp32 -> Wb2 fp16 with column permute col'=h*64+d
//  blk 320..3391 : q,k,v fp32 -> Af fp16
//  blk 3392..3407: coords -> C4 (x,y,z,|c|^2); mask -> mbias (0 / -1e30)
// ---------------------------------------------------------------------------
__global__ void __launch_bounds__(256) k_prep(
    const float* __restrict__ q, const float* __restrict__ k,
    const float* __restrict__ v, const float* __restrict__ qp,
    const float* __restrict__ kp, const float* __restrict__ vp,
    const float* __restrict__ wo, const float* __restrict__ coords,
    const unsigned char* __restrict__ maskp,
    u16* __restrict__ Pt, u16* __restrict__ Wb2, u16* __restrict__ Af,
    float4* __restrict__ C4, float* __restrict__ mbias) {
    int blk = blockIdx.x, t = threadIdx.x;
    __shared__ float lds[64 * 65];
    if (blk < 192) {
        int z = blk >> 6, rem = blk & 63, h = rem >> 3, ddt = rem & 7;
        const float* src = (z == 0 ? qp : (z == 1 ? kp : vp)) + (size_t)h * DM * DK;
        u16* dst = Pt + ((size_t)(z * H_SZ + h)) * DK * DM;
        float sc = (z == 0) ? QSC : 1.0f;
#pragma unroll
        for (int i = 0; i < 16; i++) {
            int idx = i * 256 + t;
            int rr = idx >> 6, cc = idx & 63;
            lds[cc * 65 + rr] = src[(size_t)(ddt * 64 + rr) * DK + cc];
        }
        __syncthreads();
#pragma unroll
        for (int i = 0; i < 16; i++) {
            int idx = i * 256 + t;
            int kk = idx >> 6, dd = idx & 63;
            dst[(size_t)kk * DM + ddt * 64 + dd] = f16_rn(lds[kk * 65 + dd] * sc);
        }
    } else if (blk < 320) {
        // Wb2[c][h*64+d] = wo[c][d*8+h]
        int idx8 = (blk - 192) * 256 + t;
        int base = idx8 * 8;
        int c = base >> 9, col0 = base & 511;
        int h = col0 >> 6, d0 = col0 & 63;
        s16x8 r;
#pragma unroll
        for (int i = 0; i < 8; i++)
            r[i] = (short)f16_rn(wo[(size_t)c * 512 + (d0 + i) * 8 + h]);
        *(s16x8*)(Wb2 + base) = r;
    } else if (blk < 3392) {
        size_t base = (size_t)(blk - 320) * 2048 + (size_t)t * 8;
        int z = (int)(base >> 21);
        size_t off = base & 2097151;
        const float* s = (z == 0 ? q : (z == 1 ? k : v)) + off;
        float4 f0 = *(const float4*)(s);
        float4 f1 = *(const float4*)(s + 4);
        *(s16x8*)(Af + base) = cvt8(f0, f1);
    } else {
        int i = (blk - 3392) * 256 + t;   // 0..4095 = b*2048+n
        float x = coords[(size_t)i * 3], y = coords[(size_t)i * 3 + 1], z = coords[(size_t)i * 3 + 2];
        C4[i] = make_float4(x, y, z, x * x + y * y + z * z);
        mbias[i] = maskp[i] ? -1e30f : 0.0f;
    }
}

// ---------------------------------------------------------------------------
// K1: projection GEMM (z = q/k/v), 2-phase double-buffered A staging.
// M=128, N=64, BK=64.  z==2 output transposed+j'-permuted via LDS (coalesced).
// ---------------------------------------------------------------------------
__global__ void __launch_bounds__(256) k_proj_gemm(
    const u16* __restrict__ Af, const u16* __restrict__ Pt,
    const float* __restrict__ qbias, const float* __restrict__ kbias,
    const float* __restrict__ vbias,
    u16* __restrict__ Qb, u16* __restrict__ Kb, u16* __restrict__ Vt) {
    int z = blockIdx.z;
    const u16* A = Af + (size_t)z * (4096 * 512);
    const float* bias = z == 0 ? qbias : (z == 1 ? kbias : vbias);
    const u16* Bw = Pt + (size_t)z * (512 * 512);
    int m0 = blockIdx.x * 128, c0 = blockIdx.y * 64;
    int t = threadIdx.x, w = t >> 6, l = t & 63, g = (l >> 4), cl = l & 15;
    __shared__ __align__(16) u16 a_lds[2][128 * 64];
    f32x4 acc[2][4] = {};
    int srow_b = w * 8 + (l >> 3), schk = l & 7;

#define STAGE_P(ks, buf)                                                              \
    {                                                                                 \
        _Pragma("unroll") for (int cc = 0; cc < 4; cc++) {                            \
            int row = cc * 32 + srow_b;                                               \
            const u16* gp = A + (size_t)(m0 + row) * 512 + (ks) * 64 +                \
                            ((schk ^ (row & 7)) << 3);                                \
            stage16(gp, a_lds[buf] + cc * 2048 + w * 512, l);                         \
        }                                                                             \
    }

    STAGE_P(0, 0);
    for (int ks = 0; ks < 8; ks++) {
        int cur = ks & 1;
        __syncthreads();
        if (ks < 7) STAGE_P(ks + 1, cur ^ 1);
        s16x8 bfrag[4][2];
#pragma unroll
        for (int st = 0; st < 4; st++) {
            int c = c0 + st * 16 + cl;
#pragma unroll
            for (int kk = 0; kk < 2; kk++)
                bfrag[st][kk] = *(const s16x8*)(Bw + (size_t)c * 512 + ks * 64 + kk * 32 + 8 * g);
        }
#pragma unroll
        for (int rs = 0; rs < 2; rs++) {
            int row = w * 32 + rs * 16 + cl;
#pragma unroll
            for (int kk = 0; kk < 2; kk++) {
                s16x8 afrag = *(const s16x8*)swzc(a_lds[cur], row, kk * 64 + 16 * g);
#pragma unroll
                for (int st = 0; st < 4; st++) mfma_f16(acc[rs][st], afrag, bfrag[st][kk]);
            }
        }
    }
#undef STAGE_P

    if (z == 2) {
        // epilogue transpose: Vt[bh][jt][d][j'] with j' = (j&15)*4 + (j>>4)
        int h = blockIdx.y;
        int b = m0 >> 11;
        u16* vl = a_lds[0];           // 16KB = [2 jt][64 d][64 j']
        __syncthreads();
#pragma unroll
        for (int rs = 0; rs < 2; rs++) {
#pragma unroll
            for (int st = 0; st < 4; st++) {
                int d = st * 16 + cl;
                float bv = bias[c0 + st * 16 + cl];
#pragma unroll
                for (int r = 0; r < 4; r++) {
                    int row = w * 32 + rs * 16 + 4 * g + r;   // n-local 0..127
                    int jt = row >> 6, jl = row & 63;
                    int jp = (jl & 15) * 4 + (jl >> 4);
                    vl[jt * 4096 + d * 64 + jp] = f16_rn(acc[rs][st][r] + bv);
                }
            }
        }
        __syncthreads();
        int jt = t >> 7, rem = t & 127, d = rem >> 1, qh = t & 1;
        const u16* src = vl + jt * 4096 + d * 64 + qh * 32;
        int jtile = ((m0 & 2047) >> 6) + jt;
        u16* dst = Vt + ((size_t)((b * H_SZ + h) * 32 + jtile)) * 4096 + d * 64 + qh * 32;
        *(s16x8*)(dst) = *(const s16x8*)(src);
        *(s16x8*)(dst + 8) = *(const s16x8*)(src + 8);
        *(s16x8*)(dst + 16) = *(const s16x8*)(src + 16);
        *(s16x8*)(dst + 24) = *(const s16x8*)(src + 24);
    } else {
        float bsc = (z == 0) ? QSC : 1.0f;
        u16* dst = (z == 0) ? Qb : Kb;
#pragma unroll
        for (int rs = 0; rs < 2; rs++) {
#pragma unroll
            for (int st = 0; st < 4; st++) {
                int c = c0 + st * 16 + cl;
                int h = c >> 6, kk = c & 63;
                float bv = bias[c] * bsc;
#pragma unroll
                for (int r = 0; r < 4; r++) {
                    int m = m0 + w * 32 + rs * 16 + 4 * g + r;
                    int b = m >> 11, n = m & 2047;
                    dst[((size_t)(b * H_SZ + h) * N_SZ + n) * DK + kk] = f16_rn(acc[rs][st][r] + bv);
                }
            }
        }
    }
}

// ---------------------------------------------------------------------------
// K2: fused attention, barrier-free inner loop.
// Grid 2048 blocks (XCD-chunked) x 256 thr = 4 waves. Block owns 16 q-rows;
// wave w handles j-tiles {w, w+4, ...}. K/V fragments read directly from
// global (L2-resident). P routed through per-wave 2KB LDS in j'-permuted
// layout (matches Vt). 4-way merge at end. Scores in log2 domain.
// ---------------------------------------------------------------------------
__global__ void __launch_bounds__(256, 4) k_attn(
    const u16* __restrict__ Qb, const u16* __restrict__ Kb,
    const u16* __restrict__ Vt, const float4* __restrict__ C4,
    const float* __restrict__ mbias,
    const float* __restrict__ spread_w, const float* __restrict__ beta_w,
    u16* __restrict__ Om) {
    int bid = blockIdx.x;
    int wid = (bid & 7) * 256 + (bid >> 3);          // XCD-chunked (2048 % 8 == 0)
    int qg = wid & 127, bh = wid >> 7;
    int h = bh & 7, b = bh >> 3;
    int n0 = qg * 16;
    int t = threadIdx.x, w = t >> 6, l = t & 63, g = l >> 4, cl = l & 15;

    __shared__ __align__(16) float smem[4 * 16 * 64];   // 16KB: pbuf (8KB) then merge
    __shared__ float mergeML[4][2][16];
    u16* pbufW = (u16*)smem + w * 1024;                 // per-wave 2KB

    const u16* qp = Qb + ((size_t)bh * N_SZ + n0 + cl) * DK;
    s16x8 qf0 = *(const s16x8*)(qp + 8 * g);
    s16x8 qf1 = *(const s16x8*)(qp + 32 + 8 * g);

    float sigma = 2.0f + __expf(spread_w[h]);
    float ninv2 = -0.72134752f / (sigma * sigma);       // -(log2 e)/(2 sigma^2)
    float beta = __expf(beta_w[h]);
    float rnA = 2.002002f * beta, rnB = -1.002002f * beta;
    float m2n = -2.0f * ninv2;

    float qx2[4], qy2[4], qz2[4], aR[4];
#pragma unroll
    for (int r = 0; r < 4; r++) {
        float4 c4 = C4[b * N_SZ + n0 + 4 * g + r];
        qx2[r] = c4.x * m2n; qy2[r] = c4.y * m2n; qz2[r] = c4.z * m2n;
        aR[r] = ninv2 * c4.w;
    }

    float mrun[4] = {-1e30f, -1e30f, -1e30f, -1e30f};
    float lsum[4] = {0.f, 0.f, 0.f, 0.f};
    f32x4 oacc[4] = {};

    const u16* kTile = Kb + (size_t)bh * N_SZ * DK;
    const u16* vTile = Vt + (size_t)bh * 32 * 4096;
    const float4* c4b = C4 + b * N_SZ;
    const float* mbb = mbias + b * N_SZ;

    for (int jt = w; jt < 32; jt += 4) {
        int j0 = jt * 64;
        // --- K fragments (direct global) + QK^T ---
        s16x8 kf[4][2];
#pragma unroll
        for (int st = 0; st < 4; st++) {
            const u16* kr = kTile + (size_t)(j0 + st * 16 + cl) * DK + 8 * g;
            kf[st][0] = *(const s16x8*)(kr);
            kf[st][1] = *(const s16x8*)(kr + 32);
        }
        // --- j coords / mask (issued early, consumed after mfma) ---
        float cxv[4], cyv[4], czv[4], bJ[4], mb[4];
#pragma unroll
        for (int st = 0; st < 4; st++) {
            float4 cc = c4b[j0 + st * 16 + cl];
            cxv[st] = cc.x; cyv[st] = cc.y; czv[st] = cc.z;
            bJ[st] = ninv2 * cc.w;
            mb[st] = mbb[j0 + st * 16 + cl];
        }
        f32x4 s[4];
#pragma unroll
        for (int st = 0; st < 4; st++) {
            f32x4 a = {};
            mfma_f16(a, qf0, kf[st][0]);
            mfma_f16(a, qf1, kf[st][1]);
            s[st] = a;
        }
        // --- RBF modulation (log2 domain) ---
        float sr[4][4];
#pragma unroll
        for (int st = 0; st < 4; st++) {
#pragma unroll
            for (int r = 0; r < 4; r++) {
                float arg = fmaf(qx2[r], cxv[st],
                            fmaf(qy2[r], cyv[st],
                            fmaf(qz2[r], czv[st], aR[r] + bJ[st])));
                float rb = EXP2(arg);
                float sv = s[st][r];
                sv = fmaf(fabsf(sv), fmaf(rnA, rb, rnB), sv);
                sr[st][r] = sv + mb[st];
            }
        }
        // --- online max (deferred) ---
        float tmx[4]; bool need = false;
#pragma unroll
        for (int r = 0; r < 4; r++) {
            float tm = fmaxf(fmaxf(sr[0][r], sr[1][r]), fmaxf(sr[2][r], sr[3][r]));
            tm = fmaxf(tm, __shfl_xor(tm, 1));
            tm = fmaxf(tm, __shfl_xor(tm, 2));
            tm = fmaxf(tm, __shfl_xor(tm, 4));
            tm = fmaxf(tm, __shfl_xor(tm, 8));
            tmx[r] = tm;
            need = need || (tm > mrun[r] + 8.0f);
        }
        if (__any(need)) {
#pragma unroll
            for (int r = 0; r < 4; r++) {
                float mn = fmaxf(mrun[r], tmx[r]);
                float corr = EXP2(mrun[r] - mn);
                mrun[r] = mn;
                lsum[r] *= corr;
#pragma unroll
                for (int dst = 0; dst < 4; dst++) oacc[dst][r] *= corr;
            }
        }
        // --- p = 2^(s-m), pack to f16, store j'-permuted (1 b64/row) ---
#pragma unroll
        for (int r = 0; r < 4; r++) {
            float p0 = EXP2(sr[0][r] - mrun[r]);
            float p1 = EXP2(sr[1][r] - mrun[r]);
            float p2 = EXP2(sr[2][r] - mrun[r]);
            float p3 = EXP2(sr[3][r] - mrun[r]);
            lsum[r] += (p0 + p1) + (p2 + p3);
            u32x2 pw = {pkrtz(p0, p1), pkrtz(p2, p3)};
            *(u32x2*)&pbufW[(4 * g + r) * 64 + cl * 4] = pw;
        }
        // --- PV (V' fragments direct from global, j'-permuted layout) ---
        const u16* vp_ = vTile + (size_t)jt * 4096;
#pragma unroll
        for (int ks = 0; ks < 2; ks++) {
            s16x8 pf = *(const s16x8*)&pbufW[cl * 64 + ks * 32 + 8 * g];
#pragma unroll
            for (int dst = 0; dst < 4; dst++) {
                s16x8 vf = *(const s16x8*)(vp_ + (size_t)(dst * 16 + cl) * 64 + ks * 32 + 8 * g);
                mfma_f16(oacc[dst], pf, vf);
            }
        }
    }
    // full row-sum of l (16-lane groups)
#pragma unroll
    for (int r = 0; r < 4; r++) {
        float s = lsum[r];
        s += __shfl_xor(s, 1); s += __shfl_xor(s, 2);
        s += __shfl_xor(s, 4); s += __shfl_xor(s, 8);
        lsum[r] = s;
    }
    // --- 4-way j-split merge ---
    __syncthreads();
#pragma unroll
    for (int r = 0; r < 4; r++) {
        int row = 4 * g + r;
#pragma unroll
        for (int dst = 0; dst < 4; dst++)
            smem[(w * 16 + row) * 64 + dst * 16 + cl] = oacc[dst][r];
        if (cl == 0) {
            mergeML[w][0][row] = mrun[r];
            mergeML[w][1][row] = lsum[r];
        }
    }
    __syncthreads();
#pragma unroll
    for (int rr = 0; rr < 4; rr++) {
        int row = w * 4 + rr;
        float m0_ = fmaxf(fmaxf(mergeML[0][0][row], mergeML[1][0][row]),
                          fmaxf(mergeML[2][0][row], mergeML[3][0][row]));
        float num = 0.f, den = 0.f;
#pragma unroll
        for (int js = 0; js < 4; js++) {
            float e = EXP2(mergeML[js][0][row] - m0_);
            num = fmaf(e, smem[(js * 16 + row) * 64 + l], num);
            den = fmaf(e, mergeML[js][1][row], den);
        }
        Om[((size_t)b * N_SZ + n0 + row) * DM + h * 64 + l] = f16_rn(num / den);
    }
}

// ---------------------------------------------------------------------------
// K3: out = Om(fp16, col'=h*64+d) @ Wb2^T. M=128, N=64, BK=64, 2-phase dbuf.
// ---------------------------------------------------------------------------
__global__ void __launch_bounds__(256) k_out_gemm(
    const u16* __restrict__ Om, const u16* __restrict__ Wb2,
    float* __restrict__ out) {
    int m0 = blockIdx.x * 128, c0 = blockIdx.y * 64;
    int t = threadIdx.x, w = t >> 6, l = t & 63, g = (l >> 4), cl = l & 15;
    __shared__ __align__(16) u16 a_lds[2][128 * 64];
    f32x4 acc[2][4] = {};
    int srow_b = w * 8 + (l >> 3), schk = l & 7;

#define STAGE_O(ks, buf)                                                              \
    {                                                                                 \
        _Pragma("unroll") for (int cc = 0; cc < 4; cc++) {                            \
            int row = cc * 32 + srow_b;                                               \
            const u16* gp = Om + (size_t)(m0 + row) * 512 + (ks) * 64 +               \
                            ((schk ^ (row & 7)) << 3);                                \
            stage16(gp, a_lds[buf] + cc * 2048 + w * 512, l);                         \
        }                                                                             \
    }

    STAGE_O(0, 0);
    for (int ks = 0; ks < 8; ks++) {
        int cur = ks & 1;
        __syncthreads();
        if (ks < 7) STAGE_O(ks + 1, cur ^ 1);
        s16x8 bfrag[4][2];
#pragma unroll
        for (int st = 0; st < 4; st++) {
            int c = c0 + st * 16 + cl;
#pragma unroll
            for (int kk = 0; kk < 2; kk++)
                bfrag[st][kk] = *(const s16x8*)(Wb2 + (size_t)c * 512 + ks * 64 + kk * 32 + 8 * g);
        }
#pragma unroll
        for (int rs = 0; rs < 2; rs++) {
            int row = w * 32 + rs * 16 + cl;
#pragma unroll
            for (int kk = 0; kk < 2; kk++) {
                s16x8 afrag = *(const s16x8*)swzc(a_lds[cur], row, kk * 64 + 16 * g);
#pragma unroll
                for (int st = 0; st < 4; st++) mfma_f16(acc[rs][st], afrag, bfrag[st][kk]);
            }
        }
    }
#undef STAGE_O
#pragma unroll
    for (int rs = 0; rs < 2; rs++) {
#pragma unroll
        for (int st = 0; st < 4; st++) {
            int c = c0 + st * 16 + cl;
#pragma unroll
            for (int r = 0; r < 4; r++) {
                int m = m0 + w * 32 + rs * 16 + 4 * g + r;
                out[(size_t)m * 512 + c] = acc[rs][st][r];
            }
        }
    }
}

extern "C" void kernel_launch(void* const* d_in, const int* in_sizes, int n_in,
                              void* d_out, int out_size, void* d_ws, size_t ws_size,
                              hipStream_t stream) {
    const float* q      = (const float*)d_in[0];
    const float* k      = (const float*)d_in[1];
    const float* v      = (const float*)d_in[2];
    const float* coords = (const float*)d_in[3];
    const unsigned char* mask = (const unsigned char*)d_in[4];
    const float* sw     = (const float*)d_in[5];
    const float* bw     = (const float*)d_in[6];
    const float* qp     = (const float*)d_in[7];
    const float* kp     = (const float*)d_in[8];
    const float* vp     = (const float*)d_in[9];
    const float* qbias  = (const float*)d_in[10];
    const float* kbias  = (const float*)d_in[11];
    const float* vbias  = (const float*)d_in[12];
    const float* wo     = (const float*)d_in[13];

    char* ws = (char*)d_ws;
    u16*    Pt    = (u16*)(ws);                    //  1,572,864 B
    u16*    Wb2   = (u16*)(ws + 1572864);          //    524,288 B
    u16*    Af    = (u16*)(ws + 2097152);          // 12,582,912 B
    u16*    Qb    = (u16*)(ws + 14680064);         //  4,194,304 B
    u16*    Kb    = (u16*)(ws + 18874368);         //  4,194,304 B
    u16*    Vt    = (u16*)(ws + 23068672);         //  4,194,304 B
    u16*    Om    = (u16*)(ws + 27262976);         //  4,194,304 B
    float4* C4    = (float4*)(ws + 31457280);      //     65,536 B
    float*  mbias = (float*)(ws + 31522816);       //     16,384 B

    k_prep<<<dim3(3408), 256, 0, stream>>>(q, k, v, qp, kp, vp, wo, coords, mask,
                                           Pt, Wb2, Af, C4, mbias);
    k_proj_gemm<<<dim3(32, 8, 3), 256, 0, stream>>>(Af, Pt, qbias, kbias, vbias, Qb, Kb, Vt);
    k_attn<<<dim3(2048), 256, 0, stream>>>(Qb, Kb, Vt, C4, mbias, sw, bw, Om);
    k_out_gemm<<<dim3(32, 8), 256, 0, stream>>>(Om, Wb2, (float*)d_out);
}

// Round 5
// 240.485 us; speedup vs baseline: 1.1978x; 1.1978x over previous
//
#include <hip/hip_runtime.h>
#include <hip/hip_fp16.h>

typedef unsigned short u16;
typedef unsigned int u32;
typedef __attribute__((ext_vector_type(4))) float f32x4;
typedef __attribute__((ext_vector_type(8))) short s16x8;
typedef __attribute__((ext_vector_type(2))) unsigned int u32x2;
typedef __fp16 fp16x2 __attribute__((ext_vector_type(2)));

#define B_SZ 2
#define N_SZ 2048
#define H_SZ 8
#define DK 64
#define DM 512
// 0.125 * log2(e): folds 1/sqrt(dk) AND base-e->base-2 into Q projection weights
#define QSC 0.18033688f

static __device__ inline void mfma_f16(f32x4& acc, s16x8 a, s16x8 b) {
    asm volatile("v_mfma_f32_16x16x32_f16 %0, %1, %2, %0" : "+v"(acc) : "v"(a), "v"(b));
}
static __device__ inline u16 f16_rn(float f) { return __half_as_ushort(__float2half(f)); }

static __device__ inline u32 pkrtz(float a, float b) {
    union { fp16x2 h; u32 u; } cv;
    cv.h = __builtin_amdgcn_cvt_pkrtz(a, b);
    return cv.u;
}

#if __has_builtin(__builtin_amdgcn_exp2f)
#define EXP2(x) __builtin_amdgcn_exp2f(x)
#else
#define EXP2(x) exp2f(x)
#endif

static __device__ inline s16x8 cvt8(const float4& a, const float4& b) {
    s16x8 r;
    r[0] = (short)f16_rn(a.x); r[1] = (short)f16_rn(a.y);
    r[2] = (short)f16_rn(a.z); r[3] = (short)f16_rn(a.w);
    r[4] = (short)f16_rn(b.x); r[5] = (short)f16_rn(b.y);
    r[6] = (short)f16_rn(b.z); r[7] = (short)f16_rn(b.w);
    return r;
}

// XOR swizzle for 128B LDS rows: byte ^= (row&7)<<4 (bijective per 8-row stripe)
static __device__ inline u16* swz(u16* base, int row, int byteoff) {
    return (u16*)((char*)base + row * 128 + (byteoff ^ ((row & 7) << 4)));
}
static __device__ inline const u16* swzc(const u16* base, int row, int byteoff) {
    return (const u16*)((const char*)base + row * 128 + (byteoff ^ ((row & 7) << 4)));
}

#if __has_builtin(__builtin_amdgcn_global_load_lds)
#define HAS_GLL 1
static __device__ inline void gll16(const u16* g, u16* l) {
    __builtin_amdgcn_global_load_lds(
        (const __attribute__((address_space(1))) unsigned int*)g,
        (__attribute__((address_space(3))) unsigned int*)l, 16, 0, 0);
}
#endif
static __device__ inline void stage16(const u16* gp, u16* lbase, int lane) {
#ifdef HAS_GLL
    gll16(gp, lbase);
#else
    *(s16x8*)(lbase + lane * 8) = *(const s16x8*)(gp);
#endif
}

// ---------------------------------------------------------------------------
// K0: all prep.
//  blk 0..191    : proj transpose -> Pt [(z*8+h)*64+dk][512] fp16 (z=0 scaled QSC)
//  blk 192..319  : w_out fp32 -> Wb2 fp16 with column permute col'=h*64+d
//  blk 320..3391 : q,k,v fp32 -> Af fp16
//  blk 3392..3407: coords -> C4 (x,y,z,|c|^2); mask -> mbias (0 / -1e30)
// ---------------------------------------------------------------------------
__global__ void __launch_bounds__(256) k_prep(
    const float* __restrict__ q, const float* __restrict__ k,
    const float* __restrict__ v, const float* __restrict__ qp,
    const float* __restrict__ kp, const float* __restrict__ vp,
    const float* __restrict__ wo, const float* __restrict__ coords,
    const unsigned char* __restrict__ maskp,
    u16* __restrict__ Pt, u16* __restrict__ Wb2, u16* __restrict__ Af,
    float4* __restrict__ C4, float* __restrict__ mbias) {
    int blk = blockIdx.x, t = threadIdx.x;
    __shared__ float lds[64 * 65];
    if (blk < 192) {
        int z = blk >> 6, rem = blk & 63, h = rem >> 3, ddt = rem & 7;
        const float* src = (z == 0 ? qp : (z == 1 ? kp : vp)) + (size_t)h * DM * DK;
        u16* dst = Pt + ((size_t)(z * H_SZ + h)) * DK * DM;
        float sc = (z == 0) ? QSC : 1.0f;
#pragma unroll
        for (int i = 0; i < 16; i++) {
            int idx = i * 256 + t;
            int rr = idx >> 6, cc = idx & 63;
            lds[cc * 65 + rr] = src[(size_t)(ddt * 64 + rr) * DK + cc];
        }
        __syncthreads();
#pragma unroll
        for (int i = 0; i < 16; i++) {
            int idx = i * 256 + t;
            int kk = idx >> 6, dd = idx & 63;
            dst[(size_t)kk * DM + ddt * 64 + dd] = f16_rn(lds[kk * 65 + dd] * sc);
        }
    } else if (blk < 320) {
        // Wb2[c][h*64+d] = wo[c][d*8+h]
        int idx8 = (blk - 192) * 256 + t;
        int base = idx8 * 8;
        int c = base >> 9, col0 = base & 511;
        int h = col0 >> 6, d0 = col0 & 63;
        s16x8 r;
#pragma unroll
        for (int i = 0; i < 8; i++)
            r[i] = (short)f16_rn(wo[(size_t)c * 512 + (d0 + i) * 8 + h]);
        *(s16x8*)(Wb2 + base) = r;
    } else if (blk < 3392) {
        size_t base = (size_t)(blk - 320) * 2048 + (size_t)t * 8;
        int z = (int)(base >> 21);
        size_t off = base & 2097151;
        const float* s = (z == 0 ? q : (z == 1 ? k : v)) + off;
        float4 f0 = *(const float4*)(s);
        float4 f1 = *(const float4*)(s + 4);
        *(s16x8*)(Af + base) = cvt8(f0, f1);
    } else {
        int i = (blk - 3392) * 256 + t;   // 0..4095 = b*2048+n
        float x = coords[(size_t)i * 3], y = coords[(size_t)i * 3 + 1], z = coords[(size_t)i * 3 + 2];
        C4[i] = make_float4(x, y, z, x * x + y * y + z * z);
        mbias[i] = maskp[i] ? -1e30f : 0.0f;
    }
}

// ---------------------------------------------------------------------------
// K1: projection GEMM (z = q/k/v), 2-phase double-buffered A staging.
// M=128, N=64, BK=64.  z==2 output transposed+j'-permuted via LDS (coalesced).
// ---------------------------------------------------------------------------
__global__ void __launch_bounds__(256) k_proj_gemm(
    const u16* __restrict__ Af, const u16* __restrict__ Pt,
    const float* __restrict__ qbias, const float* __restrict__ kbias,
    const float* __restrict__ vbias,
    u16* __restrict__ Qb, u16* __restrict__ Kb, u16* __restrict__ Vt) {
    int z = blockIdx.z;
    const u16* A = Af + (size_t)z * (4096 * 512);
    const float* bias = z == 0 ? qbias : (z == 1 ? kbias : vbias);
    const u16* Bw = Pt + (size_t)z * (512 * 512);
    int m0 = blockIdx.x * 128, c0 = blockIdx.y * 64;
    int t = threadIdx.x, w = t >> 6, l = t & 63, g = (l >> 4), cl = l & 15;
    __shared__ __align__(16) u16 a_lds[2][128 * 64];
    f32x4 acc[2][4] = {};
    int srow_b = w * 8 + (l >> 3), schk = l & 7;

#define STAGE_P(ks, buf)                                                              \
    {                                                                                 \
        _Pragma("unroll") for (int cc = 0; cc < 4; cc++) {                            \
            int row = cc * 32 + srow_b;                                               \
            const u16* gp = A + (size_t)(m0 + row) * 512 + (ks) * 64 +                \
                            ((schk ^ (row & 7)) << 3);                                \
            stage16(gp, a_lds[buf] + cc * 2048 + w * 512, l);                         \
        }                                                                             \
    }

    STAGE_P(0, 0);
    for (int ks = 0; ks < 8; ks++) {
        int cur = ks & 1;
        __syncthreads();
        if (ks < 7) STAGE_P(ks + 1, cur ^ 1);
        s16x8 bfrag[4][2];
#pragma unroll
        for (int st = 0; st < 4; st++) {
            int c = c0 + st * 16 + cl;
#pragma unroll
            for (int kk = 0; kk < 2; kk++)
                bfrag[st][kk] = *(const s16x8*)(Bw + (size_t)c * 512 + ks * 64 + kk * 32 + 8 * g);
        }
#pragma unroll
        for (int rs = 0; rs < 2; rs++) {
            int row = w * 32 + rs * 16 + cl;
#pragma unroll
            for (int kk = 0; kk < 2; kk++) {
                s16x8 afrag = *(const s16x8*)swzc(a_lds[cur], row, kk * 64 + 16 * g);
#pragma unroll
                for (int st = 0; st < 4; st++) mfma_f16(acc[rs][st], afrag, bfrag[st][kk]);
            }
        }
    }
#undef STAGE_P

    if (z == 2) {
        // epilogue transpose: Vt[bh][jt][d][j'] with j' = (j&15)*4 + (j>>4)
        int h = blockIdx.y;
        int b = m0 >> 11;
        u16* vl = a_lds[0];           // 16KB = [2 jt][64 d][64 j']
        __syncthreads();
#pragma unroll
        for (int rs = 0; rs < 2; rs++) {
#pragma unroll
            for (int st = 0; st < 4; st++) {
                int d = st * 16 + cl;
                float bv = bias[c0 + st * 16 + cl];
#pragma unroll
                for (int r = 0; r < 4; r++) {
                    int row = w * 32 + rs * 16 + 4 * g + r;   // n-local 0..127
                    int jt = row >> 6, jl = row & 63;
                    int jp = (jl & 15) * 4 + (jl >> 4);
                    vl[jt * 4096 + d * 64 + jp] = f16_rn(acc[rs][st][r] + bv);
                }
            }
        }
        __syncthreads();
        int jt = t >> 7, rem = t & 127, d = rem >> 1, qh = t & 1;
        const u16* src = vl + jt * 4096 + d * 64 + qh * 32;
        int jtile = ((m0 & 2047) >> 6) + jt;
        u16* dst = Vt + ((size_t)((b * H_SZ + h) * 32 + jtile)) * 4096 + d * 64 + qh * 32;
        *(s16x8*)(dst) = *(const s16x8*)(src);
        *(s16x8*)(dst + 8) = *(const s16x8*)(src + 8);
        *(s16x8*)(dst + 16) = *(const s16x8*)(src + 16);
        *(s16x8*)(dst + 24) = *(const s16x8*)(src + 24);
    } else {
        float bsc = (z == 0) ? QSC : 1.0f;
        u16* dst = (z == 0) ? Qb : Kb;
#pragma unroll
        for (int rs = 0; rs < 2; rs++) {
#pragma unroll
            for (int st = 0; st < 4; st++) {
                int c = c0 + st * 16 + cl;
                int h = c >> 6, kk = c & 63;
                float bv = bias[c] * bsc;
#pragma unroll
                for (int r = 0; r < 4; r++) {
                    int m = m0 + w * 32 + rs * 16 + 4 * g + r;
                    int b = m >> 11, n = m & 2047;
                    dst[((size_t)(b * H_SZ + h) * N_SZ + n) * DK + kk] = f16_rn(acc[rs][st][r] + bv);
                }
            }
        }
    }
}

// ---------------------------------------------------------------------------
// K2: fused attention (round-2 structure + VALU diet + async staging).
// 512 threads = 8 waves. Block owns 64 q-rows; waves 0-3 (half 0) take even
// j-tiles, waves 4-7 odd. K/V staged in XOR-swizzled LDS; T14 split: global
// loads for tile t+1 issued at top of compute(t). P packed via cvt_pkrtz in
// j'-permuted layout (matches Vt), swizzled both sides. Log2-domain softmax.
// 2-way merge at end. Om layout [b*N+n][h*64+d] fp16.
// ---------------------------------------------------------------------------
__global__ void __launch_bounds__(512, 4) k_attn(
    const u16* __restrict__ Qb, const u16* __restrict__ Kb,
    const u16* __restrict__ Vt, const float4* __restrict__ C4,
    const float* __restrict__ mbias,
    const float* __restrict__ spread_w, const float* __restrict__ beta_w,
    u16* __restrict__ Om) {
    int bid = blockIdx.x;
    int wid = (bid & 7) * 64 + (bid >> 3);      // XCD-chunked (512 % 8 == 0)
    int qt = wid & 31, bh = wid >> 5;
    int h = bh & 7, b = bh >> 3;
    int n0 = qt * 64;
    int t = threadIdx.x, w = t >> 6, l = t & 63, g = l >> 4, cl = l & 15;
    int wq = w & 3, half = w >> 2;              // half == t>>8

    __shared__ __align__(16) u16 kbuf[2][4096];
    __shared__ __align__(16) u16 vbuf[2][4096];
    __shared__ __align__(16) u16 pbuf[8][1024];
    __shared__ float4 cjs[2][64];
    __shared__ float mbs[2][64];

    int qrow = n0 + wq * 16 + cl;
    const u16* qp = Qb + ((size_t)bh * N_SZ + qrow) * DK;
    s16x8 qf0 = *(const s16x8*)(qp + 8 * g);
    s16x8 qf1 = *(const s16x8*)(qp + 32 + 8 * g);

    float sigma = 2.0f + __expf(spread_w[h]);
    float ninv2 = -0.72134752f / (sigma * sigma);   // -(log2 e)/(2 sigma^2)
    float beta = __expf(beta_w[h]);
    float rnA = 2.002002f * beta, rnB = -1.002002f * beta;
    float m2n = -2.0f * ninv2;

    float qx2[4], qy2[4], qz2[4], aR[4];
#pragma unroll
    for (int r = 0; r < 4; r++) {
        float4 c4 = C4[b * N_SZ + n0 + wq * 16 + 4 * g + r];
        qx2[r] = c4.x * m2n; qy2[r] = c4.y * m2n; qz2[r] = c4.z * m2n;
        aR[r] = ninv2 * c4.w;
    }

    float mrun[4] = {-1e30f, -1e30f, -1e30f, -1e30f};
    float lsum[4] = {0.f, 0.f, 0.f, 0.f};
    f32x4 oacc[4] = {};

    int sid = t & 255, srow = sid >> 2, sq = sid & 3;
    const u16* kbase = Kb + (size_t)bh * N_SZ * DK;
    const u16* vbase = Vt + (size_t)bh * 32 * 4096;
    const float4* c4b = C4 + b * N_SZ;
    const float* mbb = mbias + b * N_SZ;

    // T14 async-stage registers
    s16x8 kst0, kst1, vst0, vst1;
    float4 cst; float mst = 0.f;

#define LOADT(it_)                                                                  \
    {                                                                               \
        int jts = (it_) * 2 + half, j0s = jts * 64;                                 \
        const u16* ksrc = kbase + (size_t)(j0s + srow) * 64 + sq * 16;              \
        kst0 = *(const s16x8*)(ksrc);                                               \
        kst1 = *(const s16x8*)(ksrc + 8);                                           \
        const u16* vsrc = vbase + (size_t)jts * 4096 + srow * 64 + sq * 16;         \
        vst0 = *(const s16x8*)(vsrc);                                               \
        vst1 = *(const s16x8*)(vsrc + 8);                                           \
        if (sid < 64) { cst = c4b[j0s + sid]; mst = mbb[j0s + sid]; }               \
    }

    LOADT(0);
    for (int it = 0; it < 16; it++) {
        __syncthreads();
        *(s16x8*)swz(kbuf[half], srow, sq * 32)      = kst0;
        *(s16x8*)swz(kbuf[half], srow, sq * 32 + 16) = kst1;
        *(s16x8*)swz(vbuf[half], srow, sq * 32)      = vst0;
        *(s16x8*)swz(vbuf[half], srow, sq * 32 + 16) = vst1;
        if (sid < 64) { cjs[half][sid] = cst; mbs[half][sid] = mst; }
        __syncthreads();
        if (it < 15) LOADT(it + 1);

        // --- QK^T ---
        f32x4 s[4];
#pragma unroll
        for (int st = 0; st < 4; st++) {
            int jj = st * 16 + cl;
            s16x8 kf0 = *(const s16x8*)swzc(kbuf[half], jj, 16 * g);
            s16x8 kf1 = *(const s16x8*)swzc(kbuf[half], jj, 64 + 16 * g);
            f32x4 a = {};
            mfma_f16(a, qf0, kf0);
            mfma_f16(a, qf1, kf1);
            s[st] = a;
        }
        // --- RBF modulation (log2 domain) ---
        float sr[4][4];
#pragma unroll
        for (int st = 0; st < 4; st++) {
            float4 cc = cjs[half][st * 16 + cl];
            float mb = mbs[half][st * 16 + cl];
            float bJ = ninv2 * cc.w;
#pragma unroll
            for (int r = 0; r < 4; r++) {
                float arg = fmaf(qx2[r], cc.x,
                            fmaf(qy2[r], cc.y,
                            fmaf(qz2[r], cc.z, aR[r] + bJ)));
                float rb = EXP2(arg);
                float sv = s[st][r];
                sr[st][r] = fmaf(fabsf(sv), fmaf(rnA, rb, rnB), sv) + mb;
            }
        }
        // --- online max (deferred, thr=8 in log2 domain) ---
        float tmx[4]; bool need = false;
#pragma unroll
        for (int r = 0; r < 4; r++) {
            float tm = fmaxf(fmaxf(sr[0][r], sr[1][r]), fmaxf(sr[2][r], sr[3][r]));
            tm = fmaxf(tm, __shfl_xor(tm, 1));
            tm = fmaxf(tm, __shfl_xor(tm, 2));
            tm = fmaxf(tm, __shfl_xor(tm, 4));
            tm = fmaxf(tm, __shfl_xor(tm, 8));
            tmx[r] = tm;
            need = need || (tm > mrun[r] + 8.0f);
        }
        if (__any(need)) {
#pragma unroll
            for (int r = 0; r < 4; r++) {
                float mn = fmaxf(mrun[r], tmx[r]);
                float corr = EXP2(mrun[r] - mn);
                mrun[r] = mn;
                lsum[r] *= corr;
#pragma unroll
                for (int dst = 0; dst < 4; dst++) oacc[dst][r] *= corr;
            }
        }
        // --- p = 2^(s-m), pack, store j'-permuted + swizzled (1 b64/row) ---
#pragma unroll
        for (int r = 0; r < 4; r++) {
            float p0 = EXP2(sr[0][r] - mrun[r]);
            float p1 = EXP2(sr[1][r] - mrun[r]);
            float p2 = EXP2(sr[2][r] - mrun[r]);
            float p3 = EXP2(sr[3][r] - mrun[r]);
            lsum[r] += (p0 + p1) + (p2 + p3);
            u32x2 pw = {pkrtz(p0, p1), pkrtz(p2, p3)};
            *(u32x2*)swz(pbuf[w], 4 * g + r, cl * 8) = pw;
        }
        // --- PV ---
#pragma unroll
        for (int ks = 0; ks < 2; ks++) {
            s16x8 pf = *(const s16x8*)swzc(pbuf[w], cl, ks * 64 + 16 * g);
#pragma unroll
            for (int dst = 0; dst < 4; dst++) {
                s16x8 vf = *(const s16x8*)swzc(vbuf[half], dst * 16 + cl, ks * 64 + 16 * g);
                mfma_f16(oacc[dst], pf, vf);
            }
        }
    }
#undef LOADT
    // full row-sum of l (16-lane groups)
#pragma unroll
    for (int r = 0; r < 4; r++) {
        float s = lsum[r];
        s += __shfl_xor(s, 1); s += __shfl_xor(s, 2);
        s += __shfl_xor(s, 4); s += __shfl_xor(s, 8);
        lsum[r] = s;
    }
    // --- 2-way j-half merge through LDS scratch (aliases kbuf/vbuf) ---
    __syncthreads();
    float* scrO = (float*)(&kbuf[0][0]);   // [wq][16][64] fp32 = 16 KiB
    float* scrM = (float*)(&vbuf[0][0]);   // [wq][2][16]
    if (half == 1) {
#pragma unroll
        for (int r = 0; r < 4; r++) {
            int rr = 4 * g + r;
#pragma unroll
            for (int dst = 0; dst < 4; dst++)
                scrO[wq * 1024 + rr * 64 + dst * 16 + cl] = oacc[dst][r];
            if (cl == 0) {
                scrM[wq * 32 + rr] = mrun[r];
                scrM[wq * 32 + 16 + rr] = lsum[r];
            }
        }
    }
    __syncthreads();
    if (half == 0) {
#pragma unroll
        for (int r = 0; r < 4; r++) {
            int rr = 4 * g + r;
            float mu = scrM[wq * 32 + rr], lu = scrM[wq * 32 + 16 + rr];
            float M = fmaxf(mrun[r], mu);
            float pa = EXP2(mrun[r] - M), pb = EXP2(mu - M);
            float inv = 1.0f / (pa * lsum[r] + pb * lu);
            int row = n0 + wq * 16 + rr;
#pragma unroll
            for (int dst = 0; dst < 4; dst++) {
                float o = (pa * oacc[dst][r] + pb * scrO[wq * 1024 + rr * 64 + dst * 16 + cl]) * inv;
                Om[((size_t)b * N_SZ + row) * DM + h * 64 + dst * 16 + cl] = f16_rn(o);
            }
        }
    }
}

// ---------------------------------------------------------------------------
// K3: out = Om(fp16, col'=h*64+d) @ Wb2^T. M=128, N=64, BK=64, 2-phase dbuf.
// ---------------------------------------------------------------------------
__global__ void __launch_bounds__(256) k_out_gemm(
    const u16* __restrict__ Om, const u16* __restrict__ Wb2,
    float* __restrict__ out) {
    int m0 = blockIdx.x * 128, c0 = blockIdx.y * 64;
    int t = threadIdx.x, w = t >> 6, l = t & 63, g = (l >> 4), cl = l & 15;
    __shared__ __align__(16) u16 a_lds[2][128 * 64];
    f32x4 acc[2][4] = {};
    int srow_b = w * 8 + (l >> 3), schk = l & 7;

#define STAGE_O(ks, buf)                                                              \
    {                                                                                 \
        _Pragma("unroll") for (int cc = 0; cc < 4; cc++) {                            \
            int row = cc * 32 + srow_b;                                               \
            const u16* gp = Om + (size_t)(m0 + row) * 512 + (ks) * 64 +               \
                            ((schk ^ (row & 7)) << 3);                                \
            stage16(gp, a_lds[buf] + cc * 2048 + w * 512, l);                         \
        }                                                                             \
    }

    STAGE_O(0, 0);
    for (int ks = 0; ks < 8; ks++) {
        int cur = ks & 1;
        __syncthreads();
        if (ks < 7) STAGE_O(ks + 1, cur ^ 1);
        s16x8 bfrag[4][2];
#pragma unroll
        for (int st = 0; st < 4; st++) {
            int c = c0 + st * 16 + cl;
#pragma unroll
            for (int kk = 0; kk < 2; kk++)
                bfrag[st][kk] = *(const s16x8*)(Wb2 + (size_t)c * 512 + ks * 64 + kk * 32 + 8 * g);
        }
#pragma unroll
        for (int rs = 0; rs < 2; rs++) {
            int row = w * 32 + rs * 16 + cl;
#pragma unroll
            for (int kk = 0; kk < 2; kk++) {
                s16x8 afrag = *(const s16x8*)swzc(a_lds[cur], row, kk * 64 + 16 * g);
#pragma unroll
                for (int st = 0; st < 4; st++) mfma_f16(acc[rs][st], afrag, bfrag[st][kk]);
            }
        }
    }
#undef STAGE_O
#pragma unroll
    for (int rs = 0; rs < 2; rs++) {
#pragma unroll
        for (int st = 0; st < 4; st++) {
            int c = c0 + st * 16 + cl;
#pragma unroll
            for (int r = 0; r < 4; r++) {
                int m = m0 + w * 32 + rs * 16 + 4 * g + r;
                out[(size_t)m * 512 + c] = acc[rs][st][r];
            }
        }
    }
}

extern "C" void kernel_launch(void* const* d_in, const int* in_sizes, int n_in,
                              void* d_out, int out_size, void* d_ws, size_t ws_size,
                              hipStream_t stream) {
    const float* q      = (const float*)d_in[0];
    const float* k      = (const float*)d_in[1];
    const float* v      = (const float*)d_in[2];
    const float* coords = (const float*)d_in[3];
    const unsigned char* mask = (const unsigned char*)d_in[4];
    const float* sw     = (const float*)d_in[5];
    const float* bw     = (const float*)d_in[6];
    const float* qp     = (const float*)d_in[7];
    const float* kp     = (const float*)d_in[8];
    const float* vp     = (const float*)d_in[9];
    const float* qbias  = (const float*)d_in[10];
    const float* kbias  = (const float*)d_in[11];
    const float* vbias  = (const float*)d_in[12];
    const float* wo     = (const float*)d_in[13];

    char* ws = (char*)d_ws;
    u16*    Pt    = (u16*)(ws);                    //  1,572,864 B
    u16*    Wb2   = (u16*)(ws + 1572864);          //    524,288 B
    u16*    Af    = (u16*)(ws + 2097152);          // 12,582,912 B
    u16*    Qb    = (u16*)(ws + 14680064);         //  4,194,304 B
    u16*    Kb    = (u16*)(ws + 18874368);         //  4,194,304 B
    u16*    Vt    = (u16*)(ws + 23068672);         //  4,194,304 B
    u16*    Om    = (u16*)(ws + 27262976);         //  4,194,304 B
    float4* C4    = (float4*)(ws + 31457280);      //     65,536 B
    float*  mbias = (float*)(ws + 31522816);       //     16,384 B

    k_prep<<<dim3(3408), 256, 0, stream>>>(q, k, v, qp, kp, vp, wo, coords, mask,
                                           Pt, Wb2, Af, C4, mbias);
    k_proj_gemm<<<dim3(32, 8, 3), 256, 0, stream>>>(Af, Pt, qbias, kbias, vbias, Qb, Kb, Vt);
    k_attn<<<dim3(512), 512, 0, stream>>>(Qb, Kb, Vt, C4, mbias, sw, bw, Om);
    k_out_gemm<<<dim3(32, 8), 256, 0, stream>>>(Om, Wb2, (float*)d_out);
}

// Round 6
// 203.031 us; speedup vs baseline: 1.4187x; 1.1845x over previous
//
#include <hip/hip_runtime.h>
#include <hip/hip_fp16.h>

typedef unsigned short u16;
typedef unsigned int u32;
typedef __attribute__((ext_vector_type(4))) float f32x4;
typedef __attribute__((ext_vector_type(8))) short s16x8;
typedef __attribute__((ext_vector_type(2))) unsigned int u32x2;
typedef __fp16 fp16x2 __attribute__((ext_vector_type(2)));

#define B_SZ 2
#define N_SZ 2048
#define H_SZ 8
#define DK 64
#define DM 512
// 0.125 * log2(e): folds 1/sqrt(dk) AND base-e->base-2 into Q projection weights
#define QSC 0.18033688f

static __device__ inline void mfma_f16(f32x4& acc, s16x8 a, s16x8 b) {
    asm volatile("v_mfma_f32_16x16x32_f16 %0, %1, %2, %0" : "+v"(acc) : "v"(a), "v"(b));
}
static __device__ inline u16 f16_rn(float f) { return __half_as_ushort(__float2half(f)); }

static __device__ inline u32 pkrtz(float a, float b) {
    union { fp16x2 h; u32 u; } cv;
    cv.h = __builtin_amdgcn_cvt_pkrtz(a, b);
    return cv.u;
}

#if __has_builtin(__builtin_amdgcn_exp2f)
#define EXP2(x) __builtin_amdgcn_exp2f(x)
#else
#define EXP2(x) exp2f(x)
#endif

static __device__ inline s16x8 cvt8(const float4& a, const float4& b) {
    s16x8 r;
    r[0] = (short)f16_rn(a.x); r[1] = (short)f16_rn(a.y);
    r[2] = (short)f16_rn(a.z); r[3] = (short)f16_rn(a.w);
    r[4] = (short)f16_rn(b.x); r[5] = (short)f16_rn(b.y);
    r[6] = (short)f16_rn(b.z); r[7] = (short)f16_rn(b.w);
    return r;
}

// XOR swizzle for 128B LDS rows: byte ^= (row&7)<<4 (bijective per 8-row stripe)
static __device__ inline u16* swz(u16* base, int row, int byteoff) {
    return (u16*)((char*)base + row * 128 + (byteoff ^ ((row & 7) << 4)));
}
static __device__ inline const u16* swzc(const u16* base, int row, int byteoff) {
    return (const u16*)((const char*)base + row * 128 + (byteoff ^ ((row & 7) << 4)));
}

#if __has_builtin(__builtin_amdgcn_global_load_lds)
#define HAS_GLL 1
static __device__ inline void gll16(const u16* g, u16* l) {
    __builtin_amdgcn_global_load_lds(
        (const __attribute__((address_space(1))) unsigned int*)g,
        (__attribute__((address_space(3))) unsigned int*)l, 16, 0, 0);
}
#endif
static __device__ inline void stage16(const u16* gp, u16* lbase, int lane) {
#ifdef HAS_GLL
    gll16(gp, lbase);
#else
    *(s16x8*)(lbase + lane * 8) = *(const s16x8*)(gp);
#endif
}

// Stage one 64x128B tile (8KB) from global into LDS so the LDS image carries
// the XOR swizzle: linear LDS dest (wave-uniform base, lane*16 implicit) +
// inverse-swizzled global source (m173 pattern; rule 21 both-sides).
static __device__ inline void stage_tile_swz(const u16* tile, u16* lds, int wl, int lane) {
#pragma unroll
    for (int c = 0; c < 2; c++) {
        int Lb = c * 4096 + wl * 1024 + lane * 16;      // linear LDS byte offset
        int row = Lb >> 7, off = Lb & 127;
        const u16* src = tile + row * 64 + (((off ^ ((row & 7) << 4))) >> 1);
        u16* dst = (u16*)((char*)lds + c * 4096 + wl * 1024);
#ifdef HAS_GLL
        gll16(src, dst);
#else
        *(s16x8*)((char*)dst + lane * 16) = *(const s16x8*)src;
#endif
    }
}

// ---------------------------------------------------------------------------
// K0: all prep.
//  blk 0..191    : proj transpose -> Pt [(z*8+h)*64+dk][512] fp16 (z=0 scaled QSC)
//  blk 192..319  : w_out fp32 -> Wb2 fp16 with column permute col'=h*64+d
//  blk 320..3391 : q,k,v fp32 -> Af fp16
//  blk 3392..3407: coords -> C4 (x,y,z,|c|^2); mask -> mbias (0 / -1e30)
// ---------------------------------------------------------------------------
__global__ void __launch_bounds__(256) k_prep(
    const float* __restrict__ q, const float* __restrict__ k,
    const float* __restrict__ v, const float* __restrict__ qp,
    const float* __restrict__ kp, const float* __restrict__ vp,
    const float* __restrict__ wo, const float* __restrict__ coords,
    const unsigned char* __restrict__ maskp,
    u16* __restrict__ Pt, u16* __restrict__ Wb2, u16* __restrict__ Af,
    float4* __restrict__ C4, float* __restrict__ mbias) {
    int blk = blockIdx.x, t = threadIdx.x;
    __shared__ float lds[64 * 65];
    if (blk < 192) {
        int z = blk >> 6, rem = blk & 63, h = rem >> 3, ddt = rem & 7;
        const float* src = (z == 0 ? qp : (z == 1 ? kp : vp)) + (size_t)h * DM * DK;
        u16* dst = Pt + ((size_t)(z * H_SZ + h)) * DK * DM;
        float sc = (z == 0) ? QSC : 1.0f;
#pragma unroll
        for (int i = 0; i < 16; i++) {
            int idx = i * 256 + t;
            int rr = idx >> 6, cc = idx & 63;
            lds[cc * 65 + rr] = src[(size_t)(ddt * 64 + rr) * DK + cc];
        }
        __syncthreads();
#pragma unroll
        for (int i = 0; i < 16; i++) {
            int idx = i * 256 + t;
            int kk = idx >> 6, dd = idx & 63;
            dst[(size_t)kk * DM + ddt * 64 + dd] = f16_rn(lds[kk * 65 + dd] * sc);
        }
    } else if (blk < 320) {
        // Wb2[c][h*64+d] = wo[c][d*8+h]
        int idx8 = (blk - 192) * 256 + t;
        int base = idx8 * 8;
        int c = base >> 9, col0 = base & 511;
        int h = col0 >> 6, d0 = col0 & 63;
        s16x8 r;
#pragma unroll
        for (int i = 0; i < 8; i++)
            r[i] = (short)f16_rn(wo[(size_t)c * 512 + (d0 + i) * 8 + h]);
        *(s16x8*)(Wb2 + base) = r;
    } else if (blk < 3392) {
        size_t base = (size_t)(blk - 320) * 2048 + (size_t)t * 8;
        int z = (int)(base >> 21);
        size_t off = base & 2097151;
        const float* s = (z == 0 ? q : (z == 1 ? k : v)) + off;
        float4 f0 = *(const float4*)(s);
        float4 f1 = *(const float4*)(s + 4);
        *(s16x8*)(Af + base) = cvt8(f0, f1);
    } else {
        int i = (blk - 3392) * 256 + t;   // 0..4095 = b*2048+n
        float x = coords[(size_t)i * 3], y = coords[(size_t)i * 3 + 1], z = coords[(size_t)i * 3 + 2];
        C4[i] = make_float4(x, y, z, x * x + y * y + z * z);
        mbias[i] = maskp[i] ? -1e30f : 0.0f;
    }
}

// ---------------------------------------------------------------------------
// K1: projection GEMM (z = q/k/v), 2-phase double-buffered A staging.
// Linear grid 768, XCD-chunked with c-tile minor: all 8 c-blocks of an
// A-panel land on one XCD -> A fetched once from HBM per panel.
// M=128, N=64, BK=64.  z==2 output transposed+j'-permuted via LDS.
// ---------------------------------------------------------------------------
__global__ void __launch_bounds__(256) k_proj_gemm(
    const u16* __restrict__ Af, const u16* __restrict__ Pt,
    const float* __restrict__ qbias, const float* __restrict__ kbias,
    const float* __restrict__ vbias,
    u16* __restrict__ Qb, u16* __restrict__ Kb, u16* __restrict__ Vt) {
    int bid = blockIdx.x;
    int wid = (bid & 7) * 96 + (bid >> 3);          // 768 % 8 == 0, bijective
    int c0 = (wid & 7) * 64;
    int zm = wid >> 3;
    int m0 = (zm & 31) * 128;
    int z = zm >> 5;
    const u16* A = Af + (size_t)z * (4096 * 512);
    const float* bias = z == 0 ? qbias : (z == 1 ? kbias : vbias);
    const u16* Bw = Pt + (size_t)z * (512 * 512);
    int t = threadIdx.x, w = t >> 6, l = t & 63, g = (l >> 4), cl = l & 15;
    __shared__ __align__(16) u16 a_lds[2][128 * 64];
    f32x4 acc[2][4] = {};
    int srow_b = w * 8 + (l >> 3), schk = l & 7;

#define STAGE_P(ks, buf)                                                              \
    {                                                                                 \
        _Pragma("unroll") for (int cc = 0; cc < 4; cc++) {                            \
            int row = cc * 32 + srow_b;                                               \
            const u16* gp = A + (size_t)(m0 + row) * 512 + (ks) * 64 +                \
                            ((schk ^ (row & 7)) << 3);                                \
            stage16(gp, a_lds[buf] + cc * 2048 + w * 512, l);                         \
        }                                                                             \
    }

    STAGE_P(0, 0);
    for (int ks = 0; ks < 8; ks++) {
        int cur = ks & 1;
        __syncthreads();
        if (ks < 7) STAGE_P(ks + 1, cur ^ 1);
        s16x8 bfrag[4][2];
#pragma unroll
        for (int st = 0; st < 4; st++) {
            int c = c0 + st * 16 + cl;
#pragma unroll
            for (int kk = 0; kk < 2; kk++)
                bfrag[st][kk] = *(const s16x8*)(Bw + (size_t)c * 512 + ks * 64 + kk * 32 + 8 * g);
        }
#pragma unroll
        for (int rs = 0; rs < 2; rs++) {
            int row = w * 32 + rs * 16 + cl;
#pragma unroll
            for (int kk = 0; kk < 2; kk++) {
                s16x8 afrag = *(const s16x8*)swzc(a_lds[cur], row, kk * 64 + 16 * g);
#pragma unroll
                for (int st = 0; st < 4; st++) mfma_f16(acc[rs][st], afrag, bfrag[st][kk]);
            }
        }
    }
#undef STAGE_P

    if (z == 2) {
        // epilogue transpose: Vt[bh][jt][d][j'] with j' = (j&15)*4 + (j>>4)
        int h = c0 >> 6;
        int b = m0 >> 11;
        u16* vl = a_lds[0];           // 16KB = [2 jt][64 d][64 j']
        __syncthreads();
#pragma unroll
        for (int rs = 0; rs < 2; rs++) {
#pragma unroll
            for (int st = 0; st < 4; st++) {
                int d = st * 16 + cl;
                float bv = bias[c0 + st * 16 + cl];
#pragma unroll
                for (int r = 0; r < 4; r++) {
                    int row = w * 32 + rs * 16 + 4 * g + r;   // n-local 0..127
                    int jt = row >> 6, jl = row & 63;
                    int jp = (jl & 15) * 4 + (jl >> 4);
                    vl[jt * 4096 + d * 64 + jp] = f16_rn(acc[rs][st][r] + bv);
                }
            }
        }
        __syncthreads();
        int jt = t >> 7, rem = t & 127, d = rem >> 1, qh = t & 1;
        const u16* src = vl + jt * 4096 + d * 64 + qh * 32;
        int jtile = ((m0 & 2047) >> 6) + jt;
        u16* dst = Vt + ((size_t)((b * H_SZ + h) * 32 + jtile)) * 4096 + d * 64 + qh * 32;
        *(s16x8*)(dst) = *(const s16x8*)(src);
        *(s16x8*)(dst + 8) = *(const s16x8*)(src + 8);
        *(s16x8*)(dst + 16) = *(const s16x8*)(src + 16);
        *(s16x8*)(dst + 24) = *(const s16x8*)(src + 24);
    } else {
        float bsc = (z == 0) ? QSC : 1.0f;
        u16* dst = (z == 0) ? Qb : Kb;
#pragma unroll
        for (int rs = 0; rs < 2; rs++) {
#pragma unroll
            for (int st = 0; st < 4; st++) {
                int c = c0 + st * 16 + cl;
                int h = c >> 6, kk = c & 63;
                float bv = bias[c] * bsc;
#pragma unroll
                for (int r = 0; r < 4; r++) {
                    int m = m0 + w * 32 + rs * 16 + 4 * g + r;
                    int b = m >> 11, n = m & 2047;
                    dst[((size_t)(b * H_SZ + h) * N_SZ + n) * DK + kk] = f16_rn(acc[rs][st][r] + bv);
                }
            }
        }
    }
}

// ---------------------------------------------------------------------------
// K2: fused attention — m97-style 1-barrier double-buffered pipeline.
// 512 threads = 8 waves; waves 0-3 (half 0) even j-tiles, 4-7 odd. K/V staged
// via global_load_lds with pre-swizzled source (zero staging VGPRs -> no
// spill); coords/mask read direct from L2 (no LDS). LDS = 80KB exactly ->
// 2 blocks/CU. Log2-domain softmax, defer-max, packed P. 2-way merge at end.
// ---------------------------------------------------------------------------
__global__ void __launch_bounds__(512, 4) k_attn(
    const u16* __restrict__ Qb, const u16* __restrict__ Kb,
    const u16* __restrict__ Vt, const float4* __restrict__ C4,
    const float* __restrict__ mbias,
    const float* __restrict__ spread_w, const float* __restrict__ beta_w,
    u16* __restrict__ Om) {
    int bid = blockIdx.x;
    int wid = (bid & 7) * 64 + (bid >> 3);      // XCD-chunked (512 % 8 == 0)
    int qt = wid & 31, bh = wid >> 5;
    int h = bh & 7, b = bh >> 3;
    int n0 = qt * 64;
    int t = threadIdx.x, w = t >> 6, l = t & 63, g = l >> 4, cl = l & 15;
    int wq = w & 3, half = w >> 2;

    __shared__ __align__(16) u16 kbuf[2][2][4096];   // [buf][half][8KB]
    __shared__ __align__(16) u16 vbuf[2][2][4096];
    __shared__ __align__(16) u16 pbuf[8][1024];      // per-wave P tile
    // total: 32 + 32 + 16 = 80 KB -> 2 blocks/CU

    const u16* qp = Qb + ((size_t)bh * N_SZ + n0 + wq * 16 + cl) * DK;
    s16x8 qf0 = *(const s16x8*)(qp + 8 * g);
    s16x8 qf1 = *(const s16x8*)(qp + 32 + 8 * g);

    float sigma = 2.0f + __expf(spread_w[h]);
    float ninv2 = -0.72134752f / (sigma * sigma);   // -(log2 e)/(2 sigma^2)
    float beta = __expf(beta_w[h]);
    float rnA = 2.002002f * beta, rnB = -1.002002f * beta;
    float m2n = -2.0f * ninv2;

    float qx2[4], qy2[4], qz2[4], aR[4];
#pragma unroll
    for (int r = 0; r < 4; r++) {
        float4 c4 = C4[b * N_SZ + n0 + wq * 16 + 4 * g + r];
        qx2[r] = c4.x * m2n; qy2[r] = c4.y * m2n; qz2[r] = c4.z * m2n;
        aR[r] = ninv2 * c4.w;
    }

    float mrun[4] = {-1e30f, -1e30f, -1e30f, -1e30f};
    float lsum[4] = {0.f, 0.f, 0.f, 0.f};
    f32x4 oacc[4] = {};

    const u16* kbase = Kb + (size_t)bh * N_SZ * DK;
    const u16* vbase = Vt + (size_t)bh * 32 * 4096;
    const float4* c4b = C4 + b * N_SZ;
    const float* mbb = mbias + b * N_SZ;

    // prologue: stage tile 0 of this half into buf 0
    stage_tile_swz(kbase + (size_t)(half * 64) * 64, &kbuf[0][half][0], wq, l);
    stage_tile_swz(vbase + (size_t)half * 4096,      &vbuf[0][half][0], wq, l);

    for (int it = 0; it < 16; it++) {
        int cur = it & 1;
        int jt = it * 2 + half, j0 = jt * 64;
        __syncthreads();   // stage(it) landed; prev compute done
        if (it < 15) {
            int jn = jt + 2;
            stage_tile_swz(kbase + (size_t)(jn * 64) * 64, &kbuf[cur ^ 1][half][0], wq, l);
            stage_tile_swz(vbase + (size_t)jn * 4096,      &vbuf[cur ^ 1][half][0], wq, l);
        }
        // coords/mask direct from L2 (resident), issued before MFMA
        float4 ccv[4]; float mbv[4];
#pragma unroll
        for (int st = 0; st < 4; st++) {
            ccv[st] = c4b[j0 + st * 16 + cl];
            mbv[st] = mbb[j0 + st * 16 + cl];
        }
        // --- QK^T ---
        f32x4 s[4];
#pragma unroll
        for (int st = 0; st < 4; st++) {
            int jj = st * 16 + cl;
            s16x8 kf0 = *(const s16x8*)swzc(&kbuf[cur][half][0], jj, 16 * g);
            s16x8 kf1 = *(const s16x8*)swzc(&kbuf[cur][half][0], jj, 64 + 16 * g);
            f32x4 a = {};
            mfma_f16(a, qf0, kf0);
            mfma_f16(a, qf1, kf1);
            s[st] = a;
        }
        // --- RBF modulation (log2 domain) ---
        float sr[4][4];
#pragma unroll
        for (int st = 0; st < 4; st++) {
            float bJ = ninv2 * ccv[st].w;
#pragma unroll
            for (int r = 0; r < 4; r++) {
                float arg = fmaf(qx2[r], ccv[st].x,
                            fmaf(qy2[r], ccv[st].y,
                            fmaf(qz2[r], ccv[st].z, aR[r] + bJ)));
                float rb = EXP2(arg);
                float sv = s[st][r];
                sr[st][r] = fmaf(fabsf(sv), fmaf(rnA, rb, rnB), sv) + mbv[st];
            }
        }
        // --- online max (deferred, thr=8 in log2 domain) ---
        float tmx[4]; bool need = false;
#pragma unroll
        for (int r = 0; r < 4; r++) {
            float tm = fmaxf(fmaxf(sr[0][r], sr[1][r]), fmaxf(sr[2][r], sr[3][r]));
            tm = fmaxf(tm, __shfl_xor(tm, 1));
            tm = fmaxf(tm, __shfl_xor(tm, 2));
            tm = fmaxf(tm, __shfl_xor(tm, 4));
            tm = fmaxf(tm, __shfl_xor(tm, 8));
            tmx[r] = tm;
            need = need || (tm > mrun[r] + 8.0f);
        }
        if (__any(need)) {
#pragma unroll
            for (int r = 0; r < 4; r++) {
                float mn = fmaxf(mrun[r], tmx[r]);
                float corr = EXP2(mrun[r] - mn);
                mrun[r] = mn;
                lsum[r] *= corr;
#pragma unroll
                for (int dst = 0; dst < 4; dst++) oacc[dst][r] *= corr;
            }
        }
        // --- p = 2^(s-m), pack, store j'-permuted + swizzled (1 b64/row) ---
#pragma unroll
        for (int r = 0; r < 4; r++) {
            float p0 = EXP2(sr[0][r] - mrun[r]);
            float p1 = EXP2(sr[1][r] - mrun[r]);
            float p2 = EXP2(sr[2][r] - mrun[r]);
            float p3 = EXP2(sr[3][r] - mrun[r]);
            lsum[r] += (p0 + p1) + (p2 + p3);
            u32x2 pw = {pkrtz(p0, p1), pkrtz(p2, p3)};
            *(u32x2*)swz(pbuf[w], 4 * g + r, cl * 8) = pw;
        }
        // --- PV ---
#pragma unroll
        for (int ks = 0; ks < 2; ks++) {
            s16x8 pf = *(const s16x8*)swzc(pbuf[w], cl, ks * 64 + 16 * g);
#pragma unroll
            for (int dst = 0; dst < 4; dst++) {
                s16x8 vf = *(const s16x8*)swzc(&vbuf[cur][half][0], dst * 16 + cl, ks * 64 + 16 * g);
                mfma_f16(oacc[dst], pf, vf);
            }
        }
    }
    // full row-sum of l (16-lane groups)
#pragma unroll
    for (int r = 0; r < 4; r++) {
        float s = lsum[r];
        s += __shfl_xor(s, 1); s += __shfl_xor(s, 2);
        s += __shfl_xor(s, 4); s += __shfl_xor(s, 8);
        lsum[r] = s;
    }
    // --- 2-way j-half merge through LDS scratch (aliases kbuf/vbuf) ---
    __syncthreads();
    float* scrO = (float*)(&kbuf[0][0][0]);   // [wq][16][64] fp32 = 16 KiB
    float* scrM = (float*)(&vbuf[0][0][0]);   // [wq][2][16]
    if (half == 1) {
#pragma unroll
        for (int r = 0; r < 4; r++) {
            int rr = 4 * g + r;
#pragma unroll
            for (int dst = 0; dst < 4; dst++)
                scrO[wq * 1024 + rr * 64 + dst * 16 + cl] = oacc[dst][r];
            if (cl == 0) {
                scrM[wq * 32 + rr] = mrun[r];
                scrM[wq * 32 + 16 + rr] = lsum[r];
            }
        }
    }
    __syncthreads();
    if (half == 0) {
#pragma unroll
        for (int r = 0; r < 4; r++) {
            int rr = 4 * g + r;
            float mu = scrM[wq * 32 + rr], lu = scrM[wq * 32 + 16 + rr];
            float M = fmaxf(mrun[r], mu);
            float pa = EXP2(mrun[r] - M), pb = EXP2(mu - M);
            float inv = 1.0f / (pa * lsum[r] + pb * lu);
            int row = n0 + wq * 16 + rr;
#pragma unroll
            for (int dst = 0; dst < 4; dst++) {
                float o = (pa * oacc[dst][r] + pb * scrO[wq * 1024 + rr * 64 + dst * 16 + cl]) * inv;
                Om[((size_t)b * N_SZ + row) * DM + h * 64 + dst * 16 + cl] = f16_rn(o);
            }
        }
    }
}

// ---------------------------------------------------------------------------
// K3: out = Om(fp16, col'=h*64+d) @ Wb2^T. M=128, N=64, BK=64, 2-phase dbuf.
// Linear grid 256, XCD-chunked with c-tile minor (Om panel read once/XCD).
// ---------------------------------------------------------------------------
__global__ void __launch_bounds__(256) k_out_gemm(
    const u16* __restrict__ Om, const u16* __restrict__ Wb2,
    float* __restrict__ out) {
    int bid = blockIdx.x;
    int wid = (bid & 7) * 32 + (bid >> 3);          // 256 % 8 == 0, bijective
    int c0 = (wid & 7) * 64;
    int m0 = (wid >> 3) * 128;
    int t = threadIdx.x, w = t >> 6, l = t & 63, g = (l >> 4), cl = l & 15;
    __shared__ __align__(16) u16 a_lds[2][128 * 64];
    f32x4 acc[2][4] = {};
    int srow_b = w * 8 + (l >> 3), schk = l & 7;

#define STAGE_O(ks, buf)                                                              \
    {                                                                                 \
        _Pragma("unroll") for (int cc = 0; cc < 4; cc++) {                            \
            int row = cc * 32 + srow_b;                                               \
            const u16* gp = Om + (size_t)(m0 + row) * 512 + (ks) * 64 +               \
                            ((schk ^ (row & 7)) << 3);                                \
            stage16(gp, a_lds[buf] + cc * 2048 + w * 512, l);                         \
        }                                                                             \
    }

    STAGE_O(0, 0);
    for (int ks = 0; ks < 8; ks++) {
        int cur = ks & 1;
        __syncthreads();
        if (ks < 7) STAGE_O(ks + 1, cur ^ 1);
        s16x8 bfrag[4][2];
#pragma unroll
        for (int st = 0; st < 4; st++) {
            int c = c0 + st * 16 + cl;
#pragma unroll
            for (int kk = 0; kk < 2; kk++)
                bfrag[st][kk] = *(const s16x8*)(Wb2 + (size_t)c * 512 + ks * 64 + kk * 32 + 8 * g);
        }
#pragma unroll
        for (int rs = 0; rs < 2; rs++) {
            int row = w * 32 + rs * 16 + cl;
#pragma unroll
            for (int kk = 0; kk < 2; kk++) {
                s16x8 afrag = *(const s16x8*)swzc(a_lds[cur], row, kk * 64 + 16 * g);
#pragma unroll
                for (int st = 0; st < 4; st++) mfma_f16(acc[rs][st], afrag, bfrag[st][kk]);
            }
        }
    }
#undef STAGE_O
#pragma unroll
    for (int rs = 0; rs < 2; rs++) {
#pragma unroll
        for (int st = 0; st < 4; st++) {
            int c = c0 + st * 16 + cl;
#pragma unroll
            for (int r = 0; r < 4; r++) {
                int m = m0 + w * 32 + rs * 16 + 4 * g + r;
                out[(size_t)m * 512 + c] = acc[rs][st][r];
            }
        }
    }
}

extern "C" void kernel_launch(void* const* d_in, const int* in_sizes, int n_in,
                              void* d_out, int out_size, void* d_ws, size_t ws_size,
                              hipStream_t stream) {
    const float* q      = (const float*)d_in[0];
    const float* k      = (const float*)d_in[1];
    const float* v      = (const float*)d_in[2];
    const float* coords = (const float*)d_in[3];
    const unsigned char* mask = (const unsigned char*)d_in[4];
    const float* sw     = (const float*)d_in[5];
    const float* bw     = (const float*)d_in[6];
    const float* qp     = (const float*)d_in[7];
    const float* kp     = (const float*)d_in[8];
    const float* vp     = (const float*)d_in[9];
    const float* qbias  = (const float*)d_in[10];
    const float* kbias  = (const float*)d_in[11];
    const float* vbias  = (const float*)d_in[12];
    const float* wo     = (const float*)d_in[13];

    char* ws = (char*)d_ws;
    u16*    Pt    = (u16*)(ws);                    //  1,572,864 B
    u16*    Wb2   = (u16*)(ws + 1572864);          //    524,288 B
    u16*    Af    = (u16*)(ws + 2097152);          // 12,582,912 B
    u16*    Qb    = (u16*)(ws + 14680064);         //  4,194,304 B
    u16*    Kb    = (u16*)(ws + 18874368);         //  4,194,304 B
    u16*    Vt    = (u16*)(ws + 23068672);         //  4,194,304 B
    u16*    Om    = (u16*)(ws + 27262976);         //  4,194,304 B
    float4* C4    = (float4*)(ws + 31457280);      //     65,536 B
    float*  mbias = (float*)(ws + 31522816);       //     16,384 B

    k_prep<<<dim3(3408), 256, 0, stream>>>(q, k, v, qp, kp, vp, wo, coords, mask,
                                           Pt, Wb2, Af, C4, mbias);
    k_proj_gemm<<<dim3(768), 256, 0, stream>>>(Af, Pt, qbias, kbias, vbias, Qb, Kb, Vt);
    k_attn<<<dim3(512), 512, 0, stream>>>(Qb, Kb, Vt, C4, mbias, sw, bw, Om);
    k_out_gemm<<<dim3(256), 256, 0, stream>>>(Om, Wb2, (float*)d_out);
}

// Round 8
// 200.711 us; speedup vs baseline: 1.4351x; 1.0116x over previous
//
#include <hip/hip_runtime.h>
#include <hip/hip_fp16.h>

typedef unsigned short u16;
typedef unsigned int u32;
typedef __attribute__((ext_vector_type(4))) float f32x4;
typedef __attribute__((ext_vector_type(8))) short s16x8;
typedef __attribute__((ext_vector_type(2))) unsigned int u32x2;
typedef __fp16 fp16x2 __attribute__((ext_vector_type(2)));

#define B_SZ 2
#define N_SZ 2048
#define H_SZ 8
#define DK 64
#define DM 512
// 0.125 * log2(e): folds 1/sqrt(dk) AND base-e->base-2 into Q projection weights
#define QSC 0.18033688f

static __device__ inline void mfma_f16(f32x4& acc, s16x8 a, s16x8 b) {
    asm volatile("v_mfma_f32_16x16x32_f16 %0, %1, %2, %0" : "+v"(acc) : "v"(a), "v"(b));
}
static __device__ inline u16 f16_rn(float f) { return __half_as_ushort(__float2half(f)); }

static __device__ inline u32 pkrtz(float a, float b) {
    union { fp16x2 h; u32 u; } cv;
    cv.h = __builtin_amdgcn_cvt_pkrtz(a, b);
    return cv.u;
}

#if __has_builtin(__builtin_amdgcn_exp2f)
#define EXP2(x) __builtin_amdgcn_exp2f(x)
#else
#define EXP2(x) exp2f(x)
#endif

// XOR swizzle for 128B LDS rows: byte ^= (row&7)<<4 (bijective per 8-row stripe)
static __device__ inline u16* swz(u16* base, int row, int byteoff) {
    return (u16*)((char*)base + row * 128 + (byteoff ^ ((row & 7) << 4)));
}
static __device__ inline const u16* swzc(const u16* base, int row, int byteoff) {
    return (const u16*)((const char*)base + row * 128 + (byteoff ^ ((row & 7) << 4)));
}

#if __has_builtin(__builtin_amdgcn_global_load_lds)
#define HAS_GLL 1
static __device__ inline void gll16(const u16* g, u16* l) {
    __builtin_amdgcn_global_load_lds(
        (const __attribute__((address_space(1))) unsigned int*)g,
        (__attribute__((address_space(3))) unsigned int*)l, 16, 0, 0);
}
#endif
static __device__ inline void stage16(const u16* gp, u16* lbase, int lane) {
#ifdef HAS_GLL
    gll16(gp, lbase);
#else
    *(s16x8*)(lbase + lane * 8) = *(const s16x8*)(gp);
#endif
}

// Stage one 64x128B tile (8KB) from global into LDS so the LDS image carries
// the XOR swizzle: linear LDS dest + inverse-swizzled global source.
static __device__ inline void stage_tile_swz(const u16* tile, u16* lds, int wl, int lane) {
#pragma unroll
    for (int c = 0; c < 2; c++) {
        int Lb = c * 4096 + wl * 1024 + lane * 16;      // linear LDS byte offset
        int row = Lb >> 7, off = Lb & 127;
        const u16* src = tile + row * 64 + (((off ^ ((row & 7) << 4))) >> 1);
        u16* dst = (u16*)((char*)lds + c * 4096 + wl * 1024);
#ifdef HAS_GLL
        gll16(src, dst);
#else
        *(s16x8*)((char*)dst + lane * 16) = *(const s16x8*)src;
#endif
    }
}

// ---------------------------------------------------------------------------
// K0: small prep (q/k/v conversion fused into k_proj_gemm).
//  blk 0..191  : proj transpose -> Pt [(z*8+h)*64+dk][512] fp16 (z=0 scaled QSC)
//  blk 192..319: w_out fp32 -> Wb2 fp16 with column permute col'=h*64+d
//  blk 320..335: coords -> C4 (x,y,z,|c|^2) fp32; mask -> mbias (0 / -1e30)
// ---------------------------------------------------------------------------
__global__ void __launch_bounds__(256) k_prep(
    const float* __restrict__ qp, const float* __restrict__ kp,
    const float* __restrict__ vp, const float* __restrict__ wo,
    const float* __restrict__ coords, const unsigned char* __restrict__ maskp,
    u16* __restrict__ Pt, u16* __restrict__ Wb2,
    float4* __restrict__ C4, float* __restrict__ mbias) {
    int blk = blockIdx.x, t = threadIdx.x;
    __shared__ float lds[64 * 65];
    if (blk < 192) {
        int z = blk >> 6, rem = blk & 63, h = rem >> 3, ddt = rem & 7;
        const float* src = (z == 0 ? qp : (z == 1 ? kp : vp)) + (size_t)h * DM * DK;
        u16* dst = Pt + ((size_t)(z * H_SZ + h)) * DK * DM;
        float sc = (z == 0) ? QSC : 1.0f;
#pragma unroll
        for (int i = 0; i < 16; i++) {
            int idx = i * 256 + t;
            int rr = idx >> 6, cc = idx & 63;
            lds[cc * 65 + rr] = src[(size_t)(ddt * 64 + rr) * DK + cc];
        }
        __syncthreads();
#pragma unroll
        for (int i = 0; i < 16; i++) {
            int idx = i * 256 + t;
            int kk = idx >> 6, dd = idx & 63;
            dst[(size_t)kk * DM + ddt * 64 + dd] = f16_rn(lds[kk * 65 + dd] * sc);
        }
    } else if (blk < 320) {
        // Wb2[c][h*64+d] = wo[c][d*8+h]
        int idx8 = (blk - 192) * 256 + t;
        int base = idx8 * 8;
        int c = base >> 9, col0 = base & 511;
        int h = col0 >> 6, d0 = col0 & 63;
        s16x8 r;
#pragma unroll
        for (int i = 0; i < 8; i++)
            r[i] = (short)f16_rn(wo[(size_t)c * 512 + (d0 + i) * 8 + h]);
        *(s16x8*)(Wb2 + base) = r;
    } else {
        int i = (blk - 320) * 256 + t;   // 0..4095 = b*2048+n
        float x = coords[(size_t)i * 3], y = coords[(size_t)i * 3 + 1], z = coords[(size_t)i * 3 + 2];
        C4[i] = make_float4(x, y, z, x * x + y * y + z * z);
        mbias[i] = maskp[i] ? -1e30f : 0.0f;
    }
}

// ---------------------------------------------------------------------------
// K1: projection GEMM (z = q/k/v) reading fp32 inputs DIRECTLY; conversion
// fused into staging (coalesced float4 loads -> cvt_pkrtz -> swizzled
// ds_write_b64; LDS image identical to the round-6 gll-staged one).
// Linear grid 768, XCD-chunked with c-tile minor. M=128, N=64, BK=64.
// z==2 output transposed+j'-permuted via LDS.
// ---------------------------------------------------------------------------
__global__ void __launch_bounds__(256) k_proj_gemm(
    const float* __restrict__ q, const float* __restrict__ k,
    const float* __restrict__ v, const u16* __restrict__ Pt,
    const float* __restrict__ qbias, const float* __restrict__ kbias,
    const float* __restrict__ vbias,
    u16* __restrict__ Qb, u16* __restrict__ Kb, u16* __restrict__ Vt) {
    int bid = blockIdx.x;
    int wid = (bid & 7) * 96 + (bid >> 3);          // 768 % 8 == 0, bijective
    int c0 = (wid & 7) * 64;
    int zm = wid >> 3;
    int m0 = (zm & 31) * 128;
    int z = zm >> 5;
    const float* A = z == 0 ? q : (z == 1 ? k : v);
    const float* bias = z == 0 ? qbias : (z == 1 ? kbias : vbias);
    const u16* Bw = Pt + (size_t)z * (512 * 512);
    int t = threadIdx.x, w = t >> 6, l = t & 63, g = (l >> 4), cl = l & 15;
    __shared__ __align__(16) u16 a_lds[128 * 64];
    f32x4 acc[2][4] = {};
    int sr16 = t >> 4, sc16 = t & 15;   // stage: 16 rows/stripe, 16 lanes/row

    float4 f[8];
#define LOADA(ks)                                                                     \
    {                                                                                 \
        _Pragma("unroll") for (int i = 0; i < 8; i++) {                               \
            int row = i * 16 + sr16;                                                  \
            f[i] = *(const float4*)(A + (size_t)(m0 + row) * 512 + (ks) * 64 + sc16 * 4); \
        }                                                                             \
    }
#define WRITEA()                                                                      \
    {                                                                                 \
        _Pragma("unroll") for (int i = 0; i < 8; i++) {                               \
            int row = i * 16 + sr16;                                                  \
            u32x2 pw = {pkrtz(f[i].x, f[i].y), pkrtz(f[i].z, f[i].w)};                \
            *(u32x2*)swz(a_lds, row, sc16 * 8) = pw;                                  \
        }                                                                             \
    }

    LOADA(0);
    for (int ks = 0; ks < 8; ks++) {
        __syncthreads();
        WRITEA();
        if (ks < 7) LOADA(ks + 1);
        __syncthreads();
        s16x8 bfrag[4][2];
#pragma unroll
        for (int st = 0; st < 4; st++) {
            int c = c0 + st * 16 + cl;
#pragma unroll
            for (int kk = 0; kk < 2; kk++)
                bfrag[st][kk] = *(const s16x8*)(Bw + (size_t)c * 512 + ks * 64 + kk * 32 + 8 * g);
        }
#pragma unroll
        for (int rs = 0; rs < 2; rs++) {
            int row = w * 32 + rs * 16 + cl;
#pragma unroll
            for (int kk = 0; kk < 2; kk++) {
                s16x8 afrag = *(const s16x8*)swzc(a_lds, row, kk * 64 + 16 * g);
#pragma unroll
                for (int st = 0; st < 4; st++) mfma_f16(acc[rs][st], afrag, bfrag[st][kk]);
            }
        }
    }
#undef LOADA
#undef WRITEA

    if (z == 2) {
        // epilogue transpose: Vt[bh][jt][d][j'] with j' = (j&15)*4 + (j>>4)
        int h = c0 >> 6;
        int b = m0 >> 11;
        u16* vl = a_lds;              // 16KB = [2 jt][64 d][64 j']
        __syncthreads();
#pragma unroll
        for (int rs = 0; rs < 2; rs++) {
#pragma unroll
            for (int st = 0; st < 4; st++) {
                int d = st * 16 + cl;
                float bv = bias[c0 + st * 16 + cl];
#pragma unroll
                for (int r = 0; r < 4; r++) {
                    int row = w * 32 + rs * 16 + 4 * g + r;   // n-local 0..127
                    int jt = row >> 6, jl = row & 63;
                    int jp = (jl & 15) * 4 + (jl >> 4);
                    vl[jt * 4096 + d * 64 + jp] = f16_rn(acc[rs][st][r] + bv);
                }
            }
        }
        __syncthreads();
        int jt = t >> 7, rem = t & 127, d = rem >> 1, qh = t & 1;
        const u16* src = vl + jt * 4096 + d * 64 + qh * 32;
        int jtile = ((m0 & 2047) >> 6) + jt;
        u16* dst = Vt + ((size_t)((b * H_SZ + h) * 32 + jtile)) * 4096 + d * 64 + qh * 32;
        *(s16x8*)(dst) = *(const s16x8*)(src);
        *(s16x8*)(dst + 8) = *(const s16x8*)(src + 8);
        *(s16x8*)(dst + 16) = *(const s16x8*)(src + 16);
        *(s16x8*)(dst + 24) = *(const s16x8*)(src + 24);
    } else {
        float bsc = (z == 0) ? QSC : 1.0f;
        u16* dst = (z == 0) ? Qb : Kb;
#pragma unroll
        for (int rs = 0; rs < 2; rs++) {
#pragma unroll
            for (int st = 0; st < 4; st++) {
                int c = c0 + st * 16 + cl;
                int h = c >> 6, kk = c & 63;
                float bv = bias[c] * bsc;
#pragma unroll
                for (int r = 0; r < 4; r++) {
                    int m = m0 + w * 32 + rs * 16 + 4 * g + r;
                    int b = m >> 11, n = m & 2047;
                    dst[((size_t)(b * H_SZ + h) * N_SZ + n) * DK + kk] = f16_rn(acc[rs][st][r] + bv);
                }
            }
        }
    }
}

// ---------------------------------------------------------------------------
// K2: fused attention — round-6 structure (1-barrier dbuf gll pipeline, fp32
// RBF chain from C4) + T5 setprio around the MFMA clusters. 512 thr = 8 waves;
// halves split even/odd j-tiles; LDS 80KB -> 2 blocks/CU.
// ---------------------------------------------------------------------------
__global__ void __launch_bounds__(512, 4) k_attn(
    const u16* __restrict__ Qb, const u16* __restrict__ Kb,
    const u16* __restrict__ Vt, const float4* __restrict__ C4,
    const float* __restrict__ mbias,
    const float* __restrict__ spread_w, const float* __restrict__ beta_w,
    u16* __restrict__ Om) {
    int bid = blockIdx.x;
    int wid = (bid & 7) * 64 + (bid >> 3);      // XCD-chunked (512 % 8 == 0)
    int qt = wid & 31, bh = wid >> 5;
    int h = bh & 7, b = bh >> 3;
    int n0 = qt * 64;
    int t = threadIdx.x, w = t >> 6, l = t & 63, g = l >> 4, cl = l & 15;
    int wq = w & 3, half = w >> 2;

    __shared__ __align__(16) u16 kbuf[2][2][4096];   // [buf][half][8KB]
    __shared__ __align__(16) u16 vbuf[2][2][4096];
    __shared__ __align__(16) u16 pbuf[8][1024];      // per-wave P tile
    // total: 32 + 32 + 16 = 80 KB -> 2 blocks/CU

    const u16* qp = Qb + ((size_t)bh * N_SZ + n0 + wq * 16 + cl) * DK;
    s16x8 qf0 = *(const s16x8*)(qp + 8 * g);
    s16x8 qf1 = *(const s16x8*)(qp + 32 + 8 * g);

    float sigma = 2.0f + __expf(spread_w[h]);
    float ninv2 = -0.72134752f / (sigma * sigma);   // -(log2 e)/(2 sigma^2)
    float beta = __expf(beta_w[h]);
    float rnA = 2.002002f * beta, rnB = -1.002002f * beta;
    float m2n = -2.0f * ninv2;

    float qx2[4], qy2[4], qz2[4], aR[4];
#pragma unroll
    for (int r = 0; r < 4; r++) {
        float4 c4 = C4[b * N_SZ + n0 + wq * 16 + 4 * g + r];
        qx2[r] = c4.x * m2n; qy2[r] = c4.y * m2n; qz2[r] = c4.z * m2n;
        aR[r] = ninv2 * c4.w;
    }

    float mrun[4] = {-1e30f, -1e30f, -1e30f, -1e30f};
    float lsum[4] = {0.f, 0.f, 0.f, 0.f};
    f32x4 oacc[4] = {};

    const u16* kbase = Kb + (size_t)bh * N_SZ * DK;
    const u16* vbase = Vt + (size_t)bh * 32 * 4096;
    const float4* c4b = C4 + b * N_SZ;
    const float* mbb = mbias + b * N_SZ;

    // prologue: stage tile 0 of this half into buf 0
    stage_tile_swz(kbase + (size_t)(half * 64) * 64, &kbuf[0][half][0], wq, l);
    stage_tile_swz(vbase + (size_t)half * 4096,      &vbuf[0][half][0], wq, l);

    for (int it = 0; it < 16; it++) {
        int cur = it & 1;
        int jt = it * 2 + half, j0 = jt * 64;
        __syncthreads();   // stage(it) landed; prev compute done
        if (it < 15) {
            int jn = jt + 2;
            stage_tile_swz(kbase + (size_t)(jn * 64) * 64, &kbuf[cur ^ 1][half][0], wq, l);
            stage_tile_swz(vbase + (size_t)jn * 4096,      &vbuf[cur ^ 1][half][0], wq, l);
        }
        // coords/mask direct from L2 (resident), issued before MFMA
        float4 ccv[4]; float mbv[4];
#pragma unroll
        for (int st = 0; st < 4; st++) {
            ccv[st] = c4b[j0 + st * 16 + cl];
            mbv[st] = mbb[j0 + st * 16 + cl];
        }
        // --- QK^T ---
        f32x4 s[4];
        __builtin_amdgcn_s_setprio(1);
#pragma unroll
        for (int st = 0; st < 4; st++) {
            int jj = st * 16 + cl;
            s16x8 kf0 = *(const s16x8*)swzc(&kbuf[cur][half][0], jj, 16 * g);
            s16x8 kf1 = *(const s16x8*)swzc(&kbuf[cur][half][0], jj, 64 + 16 * g);
            f32x4 a = {};
            mfma_f16(a, qf0, kf0);
            mfma_f16(a, qf1, kf1);
            s[st] = a;
        }
        __builtin_amdgcn_s_setprio(0);
        // --- RBF modulation (log2 domain, fp32 chain) ---
        float sr[4][4];
#pragma unroll
        for (int st = 0; st < 4; st++) {
            float bJ = ninv2 * ccv[st].w;
#pragma unroll
            for (int r = 0; r < 4; r++) {
                float arg = fmaf(qx2[r], ccv[st].x,
                            fmaf(qy2[r], ccv[st].y,
                            fmaf(qz2[r], ccv[st].z, aR[r] + bJ)));
                float rb = EXP2(arg);
                float sv = s[st][r];
                sr[st][r] = fmaf(fabsf(sv), fmaf(rnA, rb, rnB), sv) + mbv[st];
            }
        }
        // --- online max (deferred, thr=8 in log2 domain) ---
        float tmx[4]; bool need = false;
#pragma unroll
        for (int r = 0; r < 4; r++) {
            float tm = fmaxf(fmaxf(sr[0][r], sr[1][r]), fmaxf(sr[2][r], sr[3][r]));
            tm = fmaxf(tm, __shfl_xor(tm, 1));
            tm = fmaxf(tm, __shfl_xor(tm, 2));
            tm = fmaxf(tm, __shfl_xor(tm, 4));
            tm = fmaxf(tm, __shfl_xor(tm, 8));
            tmx[r] = tm;
            need = need || (tm > mrun[r] + 8.0f);
        }
        if (__any(need)) {
#pragma unroll
            for (int r = 0; r < 4; r++) {
                float mn = fmaxf(mrun[r], tmx[r]);
                float corr = EXP2(mrun[r] - mn);
                mrun[r] = mn;
                lsum[r] *= corr;
#pragma unroll
                for (int dst = 0; dst < 4; dst++) oacc[dst][r] *= corr;
            }
        }
        // --- p = 2^(s-m), pack, store j'-permuted + swizzled (1 b64/row) ---
#pragma unroll
        for (int r = 0; r < 4; r++) {
            float p0 = EXP2(sr[0][r] - mrun[r]);
            float p1 = EXP2(sr[1][r] - mrun[r]);
            float p2 = EXP2(sr[2][r] - mrun[r]);
            float p3 = EXP2(sr[3][r] - mrun[r]);
            lsum[r] += (p0 + p1) + (p2 + p3);
            u32x2 pw = {pkrtz(p0, p1), pkrtz(p2, p3)};
            *(u32x2*)swz(pbuf[w], 4 * g + r, cl * 8) = pw;
        }
        // --- PV ---
        __builtin_amdgcn_s_setprio(1);
#pragma unroll
        for (int ks = 0; ks < 2; ks++) {
            s16x8 pf = *(const s16x8*)swzc(pbuf[w], cl, ks * 64 + 16 * g);
#pragma unroll
            for (int dst = 0; dst < 4; dst++) {
                s16x8 vf = *(const s16x8*)swzc(&vbuf[cur][half][0], dst * 16 + cl, ks * 64 + 16 * g);
                mfma_f16(oacc[dst], pf, vf);
            }
        }
        __builtin_amdgcn_s_setprio(0);
    }
    // full row-sum of l (16-lane groups)
#pragma unroll
    for (int r = 0; r < 4; r++) {
        float s = lsum[r];
        s += __shfl_xor(s, 1); s += __shfl_xor(s, 2);
        s += __shfl_xor(s, 4); s += __shfl_xor(s, 8);
        lsum[r] = s;
    }
    // --- 2-way j-half merge through LDS scratch (aliases kbuf/vbuf) ---
    __syncthreads();
    float* scrO = (float*)(&kbuf[0][0][0]);   // [wq][16][64] fp32 = 16 KiB
    float* scrM = (float*)(&vbuf[0][0][0]);   // [wq][2][16]
    if (half == 1) {
#pragma unroll
        for (int r = 0; r < 4; r++) {
            int rr = 4 * g + r;
#pragma unroll
            for (int dst = 0; dst < 4; dst++)
                scrO[wq * 1024 + rr * 64 + dst * 16 + cl] = oacc[dst][r];
            if (cl == 0) {
                scrM[wq * 32 + rr] = mrun[r];
                scrM[wq * 32 + 16 + rr] = lsum[r];
            }
        }
    }
    __syncthreads();
    if (half == 0) {
#pragma unroll
        for (int r = 0; r < 4; r++) {
            int rr = 4 * g + r;
            float mu = scrM[wq * 32 + rr], lu = scrM[wq * 32 + 16 + rr];
            float M = fmaxf(mrun[r], mu);
            float pa = EXP2(mrun[r] - M), pb = EXP2(mu - M);
            float inv = 1.0f / (pa * lsum[r] + pb * lu);
            int row = n0 + wq * 16 + rr;
#pragma unroll
            for (int dst = 0; dst < 4; dst++) {
                float o = (pa * oacc[dst][r] + pb * scrO[wq * 1024 + rr * 64 + dst * 16 + cl]) * inv;
                Om[((size_t)b * N_SZ + row) * DM + h * 64 + dst * 16 + cl] = f16_rn(o);
            }
        }
    }
}

// ---------------------------------------------------------------------------
// K3: out = Om(fp16, col'=h*64+d) @ Wb2^T. M=128, N=64, BK=64, 2-phase dbuf.
// Linear grid 256, XCD-chunked with c-tile minor (Om panel read once/XCD).
// ---------------------------------------------------------------------------
__global__ void __launch_bounds__(256) k_out_gemm(
    const u16* __restrict__ Om, const u16* __restrict__ Wb2,
    float* __restrict__ out) {
    int bid = blockIdx.x;
    int wid = (bid & 7) * 32 + (bid >> 3);          // 256 % 8 == 0, bijective
    int c0 = (wid & 7) * 64;
    int m0 = (wid >> 3) * 128;
    int t = threadIdx.x, w = t >> 6, l = t & 63, g = (l >> 4), cl = l & 15;
    __shared__ __align__(16) u16 a_lds[2][128 * 64];
    f32x4 acc[2][4] = {};
    int srow_b = w * 8 + (l >> 3), schk = l & 7;

#define STAGE_O(ks, buf)                                                              \
    {                                                                                 \
        _Pragma("unroll") for (int cc = 0; cc < 4; cc++) {                            \
            int row = cc * 32 + srow_b;                                               \
            const u16* gp = Om + (size_t)(m0 + row) * 512 + (ks) * 64 +               \
                            ((schk ^ (row & 7)) << 3);                                \
            stage16(gp, a_lds[buf] + cc * 2048 + w * 512, l);                         \
        }                                                                             \
    }

    STAGE_O(0, 0);
    for (int ks = 0; ks < 8; ks++) {
        int cur = ks & 1;
        __syncthreads();
        if (ks < 7) STAGE_O(ks + 1, cur ^ 1);
        s16x8 bfrag[4][2];
#pragma unroll
        for (int st = 0; st < 4; st++) {
            int c = c0 + st * 16 + cl;
#pragma unroll
            for (int kk = 0; kk < 2; kk++)
                bfrag[st][kk] = *(const s16x8*)(Wb2 + (size_t)c * 512 + ks * 64 + kk * 32 + 8 * g);
        }
#pragma unroll
        for (int rs = 0; rs < 2; rs++) {
            int row = w * 32 + rs * 16 + cl;
#pragma unroll
            for (int kk = 0; kk < 2; kk++) {
                s16x8 afrag = *(const s16x8*)swzc(a_lds[cur], row, kk * 64 + 16 * g);
#pragma unroll
                for (int st = 0; st < 4; st++) mfma_f16(acc[rs][st], afrag, bfrag[st][kk]);
            }
        }
    }
#undef STAGE_O
#pragma unroll
    for (int rs = 0; rs < 2; rs++) {
#pragma unroll
        for (int st = 0; st < 4; st++) {
            int c = c0 + st * 16 + cl;
#pragma unroll
            for (int r = 0; r < 4; r++) {
                int m = m0 + w * 32 + rs * 16 + 4 * g + r;
                out[(size_t)m * 512 + c] = acc[rs][st][r];
            }
        }
    }
}

extern "C" void kernel_launch(void* const* d_in, const int* in_sizes, int n_in,
                              void* d_out, int out_size, void* d_ws, size_t ws_size,
                              hipStream_t stream) {
    const float* q      = (const float*)d_in[0];
    const float* k      = (const float*)d_in[1];
    const float* v      = (const float*)d_in[2];
    const float* coords = (const float*)d_in[3];
    const unsigned char* mask = (const unsigned char*)d_in[4];
    const float* sw     = (const float*)d_in[5];
    const float* bw     = (const float*)d_in[6];
    const float* qp     = (const float*)d_in[7];
    const float* kp     = (const float*)d_in[8];
    const float* vp     = (const float*)d_in[9];
    const float* qbias  = (const float*)d_in[10];
    const float* kbias  = (const float*)d_in[11];
    const float* vbias  = (const float*)d_in[12];
    const float* wo     = (const float*)d_in[13];

    char* ws = (char*)d_ws;
    u16*    Pt    = (u16*)(ws);                    //  1,572,864 B
    u16*    Wb2   = (u16*)(ws + 1572864);          //    524,288 B
    u16*    Qb    = (u16*)(ws + 2097152);          //  4,194,304 B
    u16*    Kb    = (u16*)(ws + 6291456);          //  4,194,304 B
    u16*    Vt    = (u16*)(ws + 10485760);         //  4,194,304 B
    u16*    Om    = (u16*)(ws + 14680064);         //  4,194,304 B
    float4* C4    = (float4*)(ws + 18874368);      //     65,536 B
    float*  mbias = (float*)(ws + 18939904);       //     16,384 B  (total ~18.1 MB)

    k_prep<<<dim3(336), 256, 0, stream>>>(qp, kp, vp, wo, coords, mask,
                                          Pt, Wb2, C4, mbias);
    k_proj_gemm<<<dim3(768), 256, 0, stream>>>(q, k, v, Pt, qbias, kbias, vbias, Qb, Kb, Vt);
    k_attn<<<dim3(512), 512, 0, stream>>>(Qb, Kb, Vt, C4, mbias, sw, bw, Om);
    k_out_gemm<<<dim3(256), 256, 0, stream>>>(Om, Wb2, (float*)d_out);
}